// Round 9
// baseline (252.295 us; speedup 1.0000x reference)
//
#include <hip/hip_runtime.h>
#include <hip/hip_bf16.h>

// Problem constants
constexpr int B  = 4;
constexpr int E  = 1024;
constexpr int Wn = 2048;
constexpr int H  = 16;
constexpr int Dh = 64;   // E / H

typedef short bf16x8 __attribute__((ext_vector_type(8)));
typedef float f32x4  __attribute__((ext_vector_type(4)));

__device__ inline unsigned short f2bf(float f){
    unsigned int u = __builtin_bit_cast(unsigned int, f);
    u = (u + 0x7fffu + ((u >> 16) & 1u)) >> 16;   // RNE
    return (unsigned short)u;
}
__device__ inline float bf2f(unsigned short u){
    return __builtin_bit_cast(float, (unsigned int)u << 16);
}
__device__ inline unsigned int pack_bf16_trunc(float lo, float hi){
    return __builtin_amdgcn_perm(__builtin_bit_cast(unsigned int, hi),
                                 __builtin_bit_cast(unsigned int, lo), 0x07060302u);
}
__device__ inline float exp2_fast(float x){ return __builtin_amdgcn_exp2f(x); }

// ---------------------------------------------------------------------------
// K0: x -> xdi (bf16, columns permuted inside each 32-block for single-MFMA PV)
// ---------------------------------------------------------------------------
__global__ void k_vint(const float* __restrict__ x, unsigned short* __restrict__ xdi){
    int tid = blockIdx.x*256 + threadIdx.x;     // [row(12) | g(8)]
    int g   = tid & 255;
    int row = tid >> 8;
    int kgw = g & 3;
    int kv0 = (g >> 2) << 5;
    const float* src = x + (size_t)row*Wn + kv0 + 4*kgw;
    float4 a = *reinterpret_cast<const float4*>(src);
    float4 b = *reinterpret_cast<const float4*>(src + 16);
    union { unsigned short us[8]; uint4 v; } u;
    u.us[0]=f2bf(a.x); u.us[1]=f2bf(a.y); u.us[2]=f2bf(a.z); u.us[3]=f2bf(a.w);
    u.us[4]=f2bf(b.x); u.us[5]=f2bf(b.y); u.us[6]=f2bf(b.z); u.us[7]=f2bf(b.w);
    *reinterpret_cast<uint4*>(xdi + (size_t)row*Wn + kv0 + 8*kgw) = u.v;
}

// ---------------------------------------------------------------------------
// K1: x -> xT (K operand, unscaled) and xQ (Q operand, scaled E^-0.5*log2e)
// ---------------------------------------------------------------------------
__global__ void k_xT(const float* __restrict__ x, unsigned short* __restrict__ xT,
                     unsigned short* __restrict__ xQ){
    const float qs = 0.03125f * 1.44269504088896340736f;
    int tid = blockIdx.x*256 + threadIdx.x;
    int w   = tid & (Wn-1);
    int dg  = (tid >> 11) & 7;
    int bh  = tid >> 14;
    const float* src = x + ((size_t)bh*Dh + dg*8)*Wn + w;
    union { unsigned short us[8]; uint4 v; } u, uq;
    #pragma unroll
    for (int i = 0; i < 8; i++){
        float f = src[(size_t)i*Wn];
        u.us[i]  = f2bf(f);
        uq.us[i] = f2bf(f * qs);
    }
    size_t off = ((size_t)bh*Wn + w)*Dh + dg*8;
    *reinterpret_cast<uint4*>(xT + off) = u.v;
    *reinterpret_cast<uint4*>(xQ + off) = uq.v;
}

// ---------------------------------------------------------------------------
// K2: M_d -> MT (bf16 transposed)
// ---------------------------------------------------------------------------
__global__ void k_MT(const float* __restrict__ M, unsigned short* __restrict__ MT){
    int tid = blockIdx.x*256 + threadIdx.x;  // [eg(7) | f(10)]
    int f  = tid & (E-1);
    int eg = tid >> 10;
    union { unsigned short us[8]; uint4 v; } u;
    #pragma unroll
    for (int i = 0; i < 8; i++) u.us[i] = f2bf(M[(size_t)(eg*8+i)*E + f]);
    *reinterpret_cast<uint4*>(MT + (size_t)f*E + eg*8) = u.v;
}

// ---------------------------------------------------------------------------
// K3: flash attention, no max-tracking, KV-split heavy blocks (additive
// partials). Round-9 structure:
//  - amdgpu_waves_per_eu(4,4): VGPR cap 128, allocator targets 4 waves/SIMD,
//    so the 8 load results of a step coexist -> ONE latency per step, not 8.
//  - block = 4 waves = SAME head, 4 consecutive q-blocks of the SAME work
//    type (identical per-step K/V addresses -> 3 of 4 waves hit L1).
//  - XCD-aware mapping: head = (blockIdx&7)*8 + i/24, head-major dispatch
//    per XCD -> 1-2 heads hot per 4MB L2 instead of 64.
// Work types per head (24 blocks): j<8: A = heavy chunk0 (qb 32+4j..35+4j,
// kv [0,1024), 32 steps); then alternating B (heavy chunk1, kv [1024,q0+32],
// diag) and C (light, kv [0,q0+32], diag) in descending-work order.
// ---------------------------------------------------------------------------
struct KVf { bf16x8 k0a, k0b, k1a, k1b, v0, v1, v2, v3; };

__global__ __launch_bounds__(256)
__attribute__((amdgpu_waves_per_eu(4,4)))
void k_attn(const unsigned short* __restrict__ xT,
            const unsigned short* __restrict__ xQ,
            const unsigned short* __restrict__ xdi,
            unsigned short* __restrict__ tws,
            unsigned short* __restrict__ pacc,
            float* __restrict__ pl){
    const int lane = threadIdx.x & 63;
    const int wv   = threadIdx.x >> 6;
    const int jl = lane & 15, kg = lane >> 4;

    const int p   = blockIdx.x;
    const int xcd = p & 7;
    const int i   = p >> 3;          // 0..191
    const int hh  = i / 24;          // 0..7
    const int j   = i % 24;          // 0..23
    const int bh  = xcd*8 + hh;      // head 0..63

    int qb, kvb, kve, half;
    bool diag, heavy;
    if (j < 8){                                    // type A: heavy chunk0
        qb = 32 + j*4 + wv; kvb = 0; kve = 1024; diag = false; heavy = true; half = 0;
    } else {
        int g = 7 - ((j - 8) >> 1);                // group 7..0 (descending work)
        if (((j - 8) & 1) == 0){                   // type B: heavy chunk1
            qb = 32 + g*4 + wv; kvb = 1024; kve = qb*32; diag = true; heavy = true;  half = 1;
        } else {                                   // type C: light
            qb = g*4 + wv;      kvb = 0;    kve = qb*32; diag = true; heavy = false; half = 0;
        }
    }
    const int q0 = qb*32;
    const int steps = (kve - kvb) >> 5;             // interior step count

    const bf16x8* xQr = reinterpret_cast<const bf16x8*>(xQ + (size_t)bh*Wn*Dh);

    bf16x8 bq[2][2];
    #pragma unroll
    for (int jt = 0; jt < 2; jt++){
        bq[jt][0] = xQr[(q0+jt*16+jl)*8 + kg];
        bq[jt][1] = xQr[(q0+jt*16+jl)*8 + 4 + kg];
    }

    // ones A-fragment for the l-sum MFMA
    union { bf16x8 v; unsigned short us[8]; } ones;
    #pragma unroll
    for (int i2 = 0; i2 < 8; i2++) ones.us[i2] = 0x3F80;

    f32x4 acc[2][4] = {};
    f32x4 accl[2] = {};

    // ---- pointer setup (byte pointers, constant strides)
    const char* pK  = (const char*)xT  + (((size_t)bh*Wn + kvb + jl)*Dh + kg*8)*2;
    const char* pV0 = (const char*)xdi + (((size_t)bh*Dh +  0 + jl)*Wn + kvb + kg*8)*2;
    const char* pV1 = (const char*)xdi + (((size_t)bh*Dh + 16 + jl)*Wn + kvb + kg*8)*2;
    const char* pV2 = (const char*)xdi + (((size_t)bh*Dh + 32 + jl)*Wn + kvb + kg*8)*2;
    const char* pV3 = (const char*)xdi + (((size_t)bh*Dh + 48 + jl)*Wn + kvb + kg*8)*2;

    auto LOAD = [&]() -> KVf {
        KVf f;
        f.k0a = *reinterpret_cast<const bf16x8*>(pK);
        f.k0b = *reinterpret_cast<const bf16x8*>(pK + 64);
        f.k1a = *reinterpret_cast<const bf16x8*>(pK + 2048);
        f.k1b = *reinterpret_cast<const bf16x8*>(pK + 2112);
        f.v0  = *reinterpret_cast<const bf16x8*>(pV0);
        f.v1  = *reinterpret_cast<const bf16x8*>(pV1);
        f.v2  = *reinterpret_cast<const bf16x8*>(pV2);
        f.v3  = *reinterpret_cast<const bf16x8*>(pV3);
        pK += 4096; pV0 += 64; pV1 += 64; pV2 += 64; pV3 += 64;
        return f;
    };

    auto compute = [&](const KVf& f){
        #pragma unroll
        for (int jt = 0; jt < 2; jt++){
            f32x4 s0 = {0,0,0,0}, s1 = {0,0,0,0};
            s0 = __builtin_amdgcn_mfma_f32_16x16x32_bf16(f.k0a, bq[jt][0], s0, 0,0,0);
            s0 = __builtin_amdgcn_mfma_f32_16x16x32_bf16(f.k0b, bq[jt][1], s0, 0,0,0);
            s1 = __builtin_amdgcn_mfma_f32_16x16x32_bf16(f.k1a, bq[jt][0], s1, 0,0,0);
            s1 = __builtin_amdgcn_mfma_f32_16x16x32_bf16(f.k1b, bq[jt][1], s1, 0,0,0);

            union { bf16x8 v; unsigned int w[4]; } bp;
            bp.w[0] = pack_bf16_trunc(exp2_fast(s0[0]), exp2_fast(s0[1]));
            bp.w[1] = pack_bf16_trunc(exp2_fast(s0[2]), exp2_fast(s0[3]));
            bp.w[2] = pack_bf16_trunc(exp2_fast(s1[0]), exp2_fast(s1[1]));
            bp.w[3] = pack_bf16_trunc(exp2_fast(s1[2]), exp2_fast(s1[3]));

            accl[jt]   = __builtin_amdgcn_mfma_f32_16x16x32_bf16(ones.v, bp.v, accl[jt], 0,0,0);
            acc[jt][0] = __builtin_amdgcn_mfma_f32_16x16x32_bf16(f.v0, bp.v, acc[jt][0], 0,0,0);
            acc[jt][1] = __builtin_amdgcn_mfma_f32_16x16x32_bf16(f.v1, bp.v, acc[jt][1], 0,0,0);
            acc[jt][2] = __builtin_amdgcn_mfma_f32_16x16x32_bf16(f.v2, bp.v, acc[jt][2], 0,0,0);
            acc[jt][3] = __builtin_amdgcn_mfma_f32_16x16x32_bf16(f.v3, bp.v, acc[jt][3], 0,0,0);
        }
    };

    auto compute_diag = [&](const KVf& f){
        #pragma unroll
        for (int jt = 0; jt < 2; jt++){
            f32x4 s0 = {0,0,0,0}, s1 = {0,0,0,0};
            s0 = __builtin_amdgcn_mfma_f32_16x16x32_bf16(f.k0a, bq[jt][0], s0, 0,0,0);
            s0 = __builtin_amdgcn_mfma_f32_16x16x32_bf16(f.k0b, bq[jt][1], s0, 0,0,0);
            s1 = __builtin_amdgcn_mfma_f32_16x16x32_bf16(f.k1a, bq[jt][0], s1, 0,0,0);
            s1 = __builtin_amdgcn_mfma_f32_16x16x32_bf16(f.k1b, bq[jt][1], s1, 0,0,0);

            const int lim = 16*jt + jl;
            float pp[8];
            #pragma unroll
            for (int r = 0; r < 4; r++){
                int c = 4*kg + r;
                pp[r]   = (c      <= lim) ? exp2_fast(s0[r]) : 0.f;
                pp[4+r] = (c + 16 <= lim) ? exp2_fast(s1[r]) : 0.f;
            }
            union { bf16x8 v; unsigned int w[4]; } bp;
            bp.w[0] = pack_bf16_trunc(pp[0], pp[1]);
            bp.w[1] = pack_bf16_trunc(pp[2], pp[3]);
            bp.w[2] = pack_bf16_trunc(pp[4], pp[5]);
            bp.w[3] = pack_bf16_trunc(pp[6], pp[7]);

            accl[jt]   = __builtin_amdgcn_mfma_f32_16x16x32_bf16(ones.v, bp.v, accl[jt], 0,0,0);
            acc[jt][0] = __builtin_amdgcn_mfma_f32_16x16x32_bf16(f.v0, bp.v, acc[jt][0], 0,0,0);
            acc[jt][1] = __builtin_amdgcn_mfma_f32_16x16x32_bf16(f.v1, bp.v, acc[jt][1], 0,0,0);
            acc[jt][2] = __builtin_amdgcn_mfma_f32_16x16x32_bf16(f.v2, bp.v, acc[jt][2], 0,0,0);
            acc[jt][3] = __builtin_amdgcn_mfma_f32_16x16x32_bf16(f.v3, bp.v, acc[jt][3], 0,0,0);
        }
    };

    // ---- main loop: all 8 loads of a step issue before compute (fits the
    // 128-VGPR budget); final load is the diagonal tile when diag==true.
    for (int s = 0; s < steps; ++s){
        KVf f = LOAD();
        compute(f);
    }
    if (diag){
        KVf f = LOAD();
        compute_diag(f);
    }

    if (!heavy){
        // ---- light epilogue: normalize (accl holds column sums), write tws
        #pragma unroll
        for (int jt = 0; jt < 2; jt++){
            const float inv = 1.0f / accl[jt][0];
            unsigned short* trow = tws + ((size_t)(bh >> 4)*Wn + q0 + jt*16 + jl)*E + (bh & 15)*Dh;
            #pragma unroll
            for (int dt = 0; dt < 4; dt++){
                union { unsigned short us[4]; ushort4 v; } o;
                #pragma unroll
                for (int r = 0; r < 4; r++) o.us[r] = f2bf(acc[jt][dt][r] * inv);
                *reinterpret_cast<ushort4*>(trow + dt*16 + 4*kg) = o.v;
            }
        }
    } else {
        // ---- heavy epilogue: write bf16 acc partial + f32 l partial
        const int qh = qb - 32;
        const size_t slot = (size_t)(bh*32 + qh)*2 + half;
        if (kg == 0){
            pl[slot*32 + jl]      = accl[0][0];
            pl[slot*32 + 16 + jl] = accl[1][0];
        }
        unsigned short* pa = pacc + slot*2048;
        #pragma unroll
        for (int jt = 0; jt < 2; jt++){
            #pragma unroll
            for (int dt = 0; dt < 4; dt++){
                union { unsigned short us[4]; ushort4 v; } o;
                #pragma unroll
                for (int r = 0; r < 4; r++) o.us[r] = f2bf(acc[jt][dt][r]);
                *reinterpret_cast<ushort4*>(pa + (jt*16+jl)*64 + dt*16 + 4*kg) = o.v;
            }
        }
    }
}

// ---------------------------------------------------------------------------
// K3b: combine the two KV-chunk partials of each heavy q-block, normalize,
// write tws. 2048 tiles; block=256 handles 4 tiles (64 thr/tile).
// ---------------------------------------------------------------------------
__global__ __launch_bounds__(256) void k_reduce(const unsigned short* __restrict__ pacc,
                                                const float* __restrict__ pl,
                                                unsigned short* __restrict__ tws){
    const int g  = blockIdx.x*4 + (threadIdx.x >> 6);   // tile 0..2047
    const int t  = threadIdx.x & 63;
    const int bh = g >> 5, qh = g & 31;
    const int q  = t >> 1;
    const int dbase = (t & 1)*32;
    const size_t slot0 = (size_t)(bh*32 + qh)*2;

    const float inv = 1.0f / (pl[slot0*32 + q] + pl[(slot0+1)*32 + q]);
    const unsigned short* a0 = pacc + slot0*2048 + q*64 + dbase;

    unsigned short* tw = tws + ((size_t)(bh >> 4)*Wn + (qh+32)*32 + q)*E + (bh & 15)*Dh + dbase;
    #pragma unroll
    for (int i = 0; i < 4; i++){
        union { uint4 v; unsigned short us[8]; } r0, r1, o;
        r0.v = *reinterpret_cast<const uint4*>(a0 + i*8);
        r1.v = *reinterpret_cast<const uint4*>(a0 + 2048 + i*8);
        #pragma unroll
        for (int j = 0; j < 8; j++)
            o.us[j] = f2bf((bf2f(r0.us[j]) + bf2f(r1.us[j])) * inv);
        *reinterpret_cast<uint4*>(tw + i*8) = o.v;
    }
}

// ---------------------------------------------------------------------------
// K4: out[b][f][w] = sum_e MT[f][e] * t_ws[b][w][e] + b_d[f]
// 128x128 C-tile per block (4 waves x 64x64); register ping-pong prefetch,
// waves_per_eu(2,2) -> VGPR cap 256 so both GF sets stay allocated.
// ---------------------------------------------------------------------------
struct GF { bf16x8 am0, am1, am2, am3, bn0, bn1, bn2, bn3; };

__global__ __launch_bounds__(256)
__attribute__((amdgpu_waves_per_eu(2,2)))
void k_gemm(const unsigned short* __restrict__ MT,
            const unsigned short* __restrict__ tws,
            const float* __restrict__ bd,
            float* __restrict__ out){
    const int lane = threadIdx.x & 63;
    const int wv   = threadIdx.x >> 6;
    const int jl = lane & 15, kg = lane >> 4;
    const int blk = blockIdx.x;
    const int b  = blk >> 7;          // 128 tiles per batch
    const int t2 = blk & 127;
    const int f0 = (t2 >> 4)*128 + (wv >> 1)*64;
    const int w0 = (t2 & 15)*128 + (wv &  1)*64;

    const char* pA = (const char*)MT + (((size_t)(f0 + jl))*E + kg*8)*2;
    const char* pB = (const char*)(tws + (size_t)b*Wn*E) + (((size_t)(w0 + jl))*E + kg*8)*2;

    auto LOAD = [&]() -> GF {
        GF g;
        g.am0 = *reinterpret_cast<const bf16x8*>(pA);
        g.am1 = *reinterpret_cast<const bf16x8*>(pA + 16*E*2);
        g.am2 = *reinterpret_cast<const bf16x8*>(pA + 32*E*2);
        g.am3 = *reinterpret_cast<const bf16x8*>(pA + 48*E*2);
        g.bn0 = *reinterpret_cast<const bf16x8*>(pB);
        g.bn1 = *reinterpret_cast<const bf16x8*>(pB + 16*E*2);
        g.bn2 = *reinterpret_cast<const bf16x8*>(pB + 32*E*2);
        g.bn3 = *reinterpret_cast<const bf16x8*>(pB + 48*E*2);
        pA += 64; pB += 64;
        return g;
    };

    f32x4 acc[4][4] = {};
    auto compute = [&](const GF& g){
        const bf16x8 am[4] = {g.am0, g.am1, g.am2, g.am3};
        const bf16x8 bn[4] = {g.bn0, g.bn1, g.bn2, g.bn3};
        #pragma unroll
        for (int i = 0; i < 4; i++)
            #pragma unroll
            for (int j = 0; j < 4; j++)
                acc[i][j] = __builtin_amdgcn_mfma_f32_16x16x32_bf16(am[i], bn[j], acc[i][j], 0,0,0);
    };

    {
        GF a = LOAD();                   // E/32 = 32 steps (even)
        for (int i = 0; i < 15; ++i){
            GF bb = LOAD();
            compute(a);
            a = LOAD();
            compute(bb);
        }
        GF bb = LOAD();
        compute(a);
        compute(bb);
    }

    #pragma unroll
    for (int i = 0; i < 4; i++){
        float bias[4];
        #pragma unroll
        for (int r = 0; r < 4; r++) bias[r] = bd[f0 + i*16 + 4*kg + r];
        #pragma unroll
        for (int j = 0; j < 4; j++){
            #pragma unroll
            for (int r = 0; r < 4; r++){
                out[((size_t)b*E + f0 + i*16 + 4*kg + r)*Wn + w0 + j*16 + jl]
                    = acc[i][j][r] + bias[r];
            }
        }
    }
}

// ---------------------------------------------------------------------------
extern "C" void kernel_launch(void* const* d_in, const int* in_sizes, int n_in,
                              void* d_out, int out_size, void* d_ws, size_t ws_size,
                              hipStream_t stream) {
    const float* x  = (const float*)d_in[0];   // (B,E,W)
    const float* Md = (const float*)d_in[1];   // (E,E)
    const float* bd = (const float*)d_in[2];   // (E,)
    float* out = (float*)d_out;                // (B,E,W)

    char* ws = (char*)d_ws;
    unsigned short* xT   = (unsigned short*)(ws);                    // 16 MB
    unsigned short* xQ   = (unsigned short*)(ws + (16u << 20));      // 16 MB
    unsigned short* xdi  = (unsigned short*)(ws + (32u << 20));      // 16 MB
    unsigned short* MT   = (unsigned short*)(ws + (48u << 20));      //  2 MB
    unsigned short* tws  = (unsigned short*)(ws + (50u << 20));      // 16 MB
    float*          pl   = (float*)(ws + (66u << 20));               // 512 KB
    unsigned short* pacc = (unsigned short*)(ws + (67u << 20));      // 16 MB

    hipLaunchKernelGGL(k_vint,   dim3(4096), dim3(256), 0, stream, x, xdi);
    hipLaunchKernelGGL(k_xT,     dim3(4096), dim3(256), 0, stream, x, xT, xQ);
    hipLaunchKernelGGL(k_MT,     dim3(512),  dim3(256), 0, stream, Md, MT);
    hipLaunchKernelGGL(k_attn,   dim3(1536), dim3(256), 0, stream, xT, xQ, xdi, tws, pacc, pl);
    hipLaunchKernelGGL(k_reduce, dim3(512),  dim3(256), 0, stream, pacc, pl, tws);
    hipLaunchKernelGGL(k_gemm,   dim3(B*(E/128)*(Wn/128)), dim3(256), 0, stream, MT, tws, bd, out);
}

// Round 10
// 250.641 us; speedup vs baseline: 1.0066x; 1.0066x over previous
//
#include <hip/hip_runtime.h>
#include <hip/hip_bf16.h>

// Problem constants
constexpr int B  = 4;
constexpr int E  = 1024;
constexpr int Wn = 2048;
constexpr int H  = 16;
constexpr int Dh = 64;   // E / H

typedef short bf16x8 __attribute__((ext_vector_type(8)));
typedef float f32x4  __attribute__((ext_vector_type(4)));

__device__ inline unsigned short f2bf(float f){
    unsigned int u = __builtin_bit_cast(unsigned int, f);
    u = (u + 0x7fffu + ((u >> 16) & 1u)) >> 16;   // RNE
    return (unsigned short)u;
}
__device__ inline float bf2f(unsigned short u){
    return __builtin_bit_cast(float, (unsigned int)u << 16);
}
__device__ inline unsigned int pack_bf16_trunc(float lo, float hi){
    return __builtin_amdgcn_perm(__builtin_bit_cast(unsigned int, hi),
                                 __builtin_bit_cast(unsigned int, lo), 0x07060302u);
}
__device__ inline float exp2_fast(float x){ return __builtin_amdgcn_exp2f(x); }

// Inline-asm 16B load: cannot be sunk/split by the scheduler; result regs
// stay live from issue to use. Wait is hand-placed (counted vmcnt).
#define GLOAD(dst, ptr, OFFSTR) \
    asm volatile("global_load_dwordx4 %0, %1, off offset:" OFFSTR \
                 : "=v"(dst) : "v"(ptr) : "memory")
// Counted wait + scheduling fence (rule #18: MFMA hoists past bare waitcnt)
#define VMWAIT(NSTR) do { \
    asm volatile("s_waitcnt vmcnt(" NSTR ")" ::: "memory"); \
    __builtin_amdgcn_sched_barrier(0); } while (0)

// ---------------------------------------------------------------------------
// K0: x -> xdi (bf16, columns permuted inside each 32-block for single-MFMA PV)
// ---------------------------------------------------------------------------
__global__ void k_vint(const float* __restrict__ x, unsigned short* __restrict__ xdi){
    int tid = blockIdx.x*256 + threadIdx.x;     // [row(12) | g(8)]
    int g   = tid & 255;
    int row = tid >> 8;
    int kgw = g & 3;
    int kv0 = (g >> 2) << 5;
    const float* src = x + (size_t)row*Wn + kv0 + 4*kgw;
    float4 a = *reinterpret_cast<const float4*>(src);
    float4 b = *reinterpret_cast<const float4*>(src + 16);
    union { unsigned short us[8]; uint4 v; } u;
    u.us[0]=f2bf(a.x); u.us[1]=f2bf(a.y); u.us[2]=f2bf(a.z); u.us[3]=f2bf(a.w);
    u.us[4]=f2bf(b.x); u.us[5]=f2bf(b.y); u.us[6]=f2bf(b.z); u.us[7]=f2bf(b.w);
    *reinterpret_cast<uint4*>(xdi + (size_t)row*Wn + kv0 + 8*kgw) = u.v;
}

// ---------------------------------------------------------------------------
// K1: x -> xT (K operand, unscaled) and xQ (Q operand, scaled E^-0.5*log2e)
// ---------------------------------------------------------------------------
__global__ void k_xT(const float* __restrict__ x, unsigned short* __restrict__ xT,
                     unsigned short* __restrict__ xQ){
    const float qs = 0.03125f * 1.44269504088896340736f;
    int tid = blockIdx.x*256 + threadIdx.x;
    int w   = tid & (Wn-1);
    int dg  = (tid >> 11) & 7;
    int bh  = tid >> 14;
    const float* src = x + ((size_t)bh*Dh + dg*8)*Wn + w;
    union { unsigned short us[8]; uint4 v; } u, uq;
    #pragma unroll
    for (int i = 0; i < 8; i++){
        float f = src[(size_t)i*Wn];
        u.us[i]  = f2bf(f);
        uq.us[i] = f2bf(f * qs);
    }
    size_t off = ((size_t)bh*Wn + w)*Dh + dg*8;
    *reinterpret_cast<uint4*>(xT + off) = u.v;
    *reinterpret_cast<uint4*>(xQ + off) = uq.v;
}

// ---------------------------------------------------------------------------
// K2: M_d -> MT (bf16 transposed)
// ---------------------------------------------------------------------------
__global__ void k_MT(const float* __restrict__ M, unsigned short* __restrict__ MT){
    int tid = blockIdx.x*256 + threadIdx.x;  // [eg(7) | f(10)]
    int f  = tid & (E-1);
    int eg = tid >> 10;
    union { unsigned short us[8]; uint4 v; } u;
    #pragma unroll
    for (int i = 0; i < 8; i++) u.us[i] = f2bf(M[(size_t)(eg*8+i)*E + f]);
    *reinterpret_cast<uint4*>(MT + (size_t)f*E + eg*8) = u.v;
}

// ---------------------------------------------------------------------------
// K3: flash attention, no max-tracking, KV-split heavy blocks (additive
// partials). Round-10: inline-asm loads + counted vmcnt ping-pong.
//  - 8 asm global_load_dwordx4 per tile, issued one tile ahead;
//    s_waitcnt vmcnt(8) waits only for the PREVIOUS tile's loads.
//  - sched_barrier(0) after each wait (MFMA would hoist past it otherwise).
//  - XCD-aware mapping (r9, kept: FETCH 40->24.6MB).
// ---------------------------------------------------------------------------
struct KVf { bf16x8 k0a, k0b, k1a, k1b, v0, v1, v2, v3; };

__global__ __launch_bounds__(256)
void k_attn(const unsigned short* __restrict__ xT,
            const unsigned short* __restrict__ xQ,
            const unsigned short* __restrict__ xdi,
            unsigned short* __restrict__ tws,
            unsigned short* __restrict__ pacc,
            float* __restrict__ pl){
    const int lane = threadIdx.x & 63;
    const int wv   = threadIdx.x >> 6;
    const int jl = lane & 15, kg = lane >> 4;

    const int p   = blockIdx.x;
    const int xcd = p & 7;
    const int i   = p >> 3;          // 0..191
    const int hh  = i / 24;          // 0..7
    const int j   = i % 24;          // 0..23
    const int bh  = xcd*8 + hh;      // head 0..63

    int qb, kvb, kve, half;
    bool diag, heavy;
    if (j < 8){                                    // type A: heavy chunk0
        qb = 32 + j*4 + wv; kvb = 0; kve = 1024; diag = false; heavy = true; half = 0;
    } else {
        int g = 7 - ((j - 8) >> 1);                // group 7..0 (descending work)
        if (((j - 8) & 1) == 0){                   // type B: heavy chunk1
            qb = 32 + g*4 + wv; kvb = 1024; kve = qb*32; diag = true; heavy = true;  half = 1;
        } else {                                   // type C: light
            qb = g*4 + wv;      kvb = 0;    kve = qb*32; diag = true; heavy = false; half = 0;
        }
    }
    const int q0 = qb*32;
    const int steps = (kve - kvb) >> 5;             // interior step count

    const bf16x8* xQr = reinterpret_cast<const bf16x8*>(xQ + (size_t)bh*Wn*Dh);

    bf16x8 bq[2][2];
    #pragma unroll
    for (int jt = 0; jt < 2; jt++){
        bq[jt][0] = xQr[(q0+jt*16+jl)*8 + kg];
        bq[jt][1] = xQr[(q0+jt*16+jl)*8 + 4 + kg];
    }

    // ones A-fragment for the l-sum MFMA
    union { bf16x8 v; unsigned short us[8]; } ones;
    #pragma unroll
    for (int i2 = 0; i2 < 8; i2++) ones.us[i2] = 0x3F80;

    f32x4 acc[2][4] = {};
    f32x4 accl[2] = {};

    // ---- pointer setup (byte pointers, constant strides)
    const char* pK  = (const char*)xT  + (((size_t)bh*Wn + kvb + jl)*Dh + kg*8)*2;
    const char* pV0 = (const char*)xdi + (((size_t)bh*Dh +  0 + jl)*Wn + kvb + kg*8)*2;
    const char* pV1 = (const char*)xdi + (((size_t)bh*Dh + 16 + jl)*Wn + kvb + kg*8)*2;
    const char* pV2 = (const char*)xdi + (((size_t)bh*Dh + 32 + jl)*Wn + kvb + kg*8)*2;
    const char* pV3 = (const char*)xdi + (((size_t)bh*Dh + 48 + jl)*Wn + kvb + kg*8)*2;

    auto LOAD = [&](KVf& f){
        GLOAD(f.k0a, pK,  "0");
        GLOAD(f.k0b, pK,  "64");
        GLOAD(f.k1a, pK,  "2048");
        GLOAD(f.k1b, pK,  "2112");
        GLOAD(f.v0,  pV0, "0");
        GLOAD(f.v1,  pV1, "0");
        GLOAD(f.v2,  pV2, "0");
        GLOAD(f.v3,  pV3, "0");
        pK += 4096; pV0 += 64; pV1 += 64; pV2 += 64; pV3 += 64;
    };

    auto compute = [&](const KVf& f){
        #pragma unroll
        for (int jt = 0; jt < 2; jt++){
            f32x4 s0 = {0,0,0,0}, s1 = {0,0,0,0};
            s0 = __builtin_amdgcn_mfma_f32_16x16x32_bf16(f.k0a, bq[jt][0], s0, 0,0,0);
            s0 = __builtin_amdgcn_mfma_f32_16x16x32_bf16(f.k0b, bq[jt][1], s0, 0,0,0);
            s1 = __builtin_amdgcn_mfma_f32_16x16x32_bf16(f.k1a, bq[jt][0], s1, 0,0,0);
            s1 = __builtin_amdgcn_mfma_f32_16x16x32_bf16(f.k1b, bq[jt][1], s1, 0,0,0);

            union { bf16x8 v; unsigned int w[4]; } bp;
            bp.w[0] = pack_bf16_trunc(exp2_fast(s0[0]), exp2_fast(s0[1]));
            bp.w[1] = pack_bf16_trunc(exp2_fast(s0[2]), exp2_fast(s0[3]));
            bp.w[2] = pack_bf16_trunc(exp2_fast(s1[0]), exp2_fast(s1[1]));
            bp.w[3] = pack_bf16_trunc(exp2_fast(s1[2]), exp2_fast(s1[3]));

            accl[jt]   = __builtin_amdgcn_mfma_f32_16x16x32_bf16(ones.v, bp.v, accl[jt], 0,0,0);
            acc[jt][0] = __builtin_amdgcn_mfma_f32_16x16x32_bf16(f.v0, bp.v, acc[jt][0], 0,0,0);
            acc[jt][1] = __builtin_amdgcn_mfma_f32_16x16x32_bf16(f.v1, bp.v, acc[jt][1], 0,0,0);
            acc[jt][2] = __builtin_amdgcn_mfma_f32_16x16x32_bf16(f.v2, bp.v, acc[jt][2], 0,0,0);
            acc[jt][3] = __builtin_amdgcn_mfma_f32_16x16x32_bf16(f.v3, bp.v, acc[jt][3], 0,0,0);
        }
    };

    auto compute_diag = [&](const KVf& f){
        #pragma unroll
        for (int jt = 0; jt < 2; jt++){
            f32x4 s0 = {0,0,0,0}, s1 = {0,0,0,0};
            s0 = __builtin_amdgcn_mfma_f32_16x16x32_bf16(f.k0a, bq[jt][0], s0, 0,0,0);
            s0 = __builtin_amdgcn_mfma_f32_16x16x32_bf16(f.k0b, bq[jt][1], s0, 0,0,0);
            s1 = __builtin_amdgcn_mfma_f32_16x16x32_bf16(f.k1a, bq[jt][0], s1, 0,0,0);
            s1 = __builtin_amdgcn_mfma_f32_16x16x32_bf16(f.k1b, bq[jt][1], s1, 0,0,0);

            const int lim = 16*jt + jl;
            float pp[8];
            #pragma unroll
            for (int r = 0; r < 4; r++){
                int c = 4*kg + r;
                pp[r]   = (c      <= lim) ? exp2_fast(s0[r]) : 0.f;
                pp[4+r] = (c + 16 <= lim) ? exp2_fast(s1[r]) : 0.f;
            }
            union { bf16x8 v; unsigned int w[4]; } bp;
            bp.w[0] = pack_bf16_trunc(pp[0], pp[1]);
            bp.w[1] = pack_bf16_trunc(pp[2], pp[3]);
            bp.w[2] = pack_bf16_trunc(pp[4], pp[5]);
            bp.w[3] = pack_bf16_trunc(pp[6], pp[7]);

            accl[jt]   = __builtin_amdgcn_mfma_f32_16x16x32_bf16(ones.v, bp.v, accl[jt], 0,0,0);
            acc[jt][0] = __builtin_amdgcn_mfma_f32_16x16x32_bf16(f.v0, bp.v, acc[jt][0], 0,0,0);
            acc[jt][1] = __builtin_amdgcn_mfma_f32_16x16x32_bf16(f.v1, bp.v, acc[jt][1], 0,0,0);
            acc[jt][2] = __builtin_amdgcn_mfma_f32_16x16x32_bf16(f.v2, bp.v, acc[jt][2], 0,0,0);
            acc[jt][3] = __builtin_amdgcn_mfma_f32_16x16x32_bf16(f.v3, bp.v, acc[jt][3], 0,0,0);
        }
    };

    // ---- counted-vmcnt ping-pong: loads run one tile ahead, never drained
    // to 0 in the steady state; no register copies (a/b alternate by role).
    {
        KVf a, b;
        if (steps == 0){
            // diag-only work item (type B qb=32, type C qb=0)
            LOAD(a); VMWAIT("0"); compute_diag(a);
        } else {
            LOAD(a);
            int rem = steps - 1;          // interior tiles still to load
            while (rem >= 2){
                LOAD(b); VMWAIT("8"); compute(a);
                LOAD(a); VMWAIT("8"); compute(b);
                rem -= 2;
            }
            if (rem == 1){
                LOAD(b); VMWAIT("8"); compute(a);
                if (diag){ LOAD(a); VMWAIT("8"); compute(b); VMWAIT("0"); compute_diag(a); }
                else     { VMWAIT("0"); compute(b); }
            } else {
                if (diag){ LOAD(b); VMWAIT("8"); compute(a); VMWAIT("0"); compute_diag(b); }
                else     { VMWAIT("0"); compute(a); }
            }
        }
    }

    if (!heavy){
        // ---- light epilogue: normalize (accl holds column sums), write tws
        #pragma unroll
        for (int jt = 0; jt < 2; jt++){
            const float inv = 1.0f / accl[jt][0];
            unsigned short* trow = tws + ((size_t)(bh >> 4)*Wn + q0 + jt*16 + jl)*E + (bh & 15)*Dh;
            #pragma unroll
            for (int dt = 0; dt < 4; dt++){
                union { unsigned short us[4]; ushort4 v; } o;
                #pragma unroll
                for (int r = 0; r < 4; r++) o.us[r] = f2bf(acc[jt][dt][r] * inv);
                *reinterpret_cast<ushort4*>(trow + dt*16 + 4*kg) = o.v;
            }
        }
    } else {
        // ---- heavy epilogue: write bf16 acc partial + f32 l partial
        const int qh = qb - 32;
        const size_t slot = (size_t)(bh*32 + qh)*2 + half;
        if (kg == 0){
            pl[slot*32 + jl]      = accl[0][0];
            pl[slot*32 + 16 + jl] = accl[1][0];
        }
        unsigned short* pa = pacc + slot*2048;
        #pragma unroll
        for (int jt = 0; jt < 2; jt++){
            #pragma unroll
            for (int dt = 0; dt < 4; dt++){
                union { unsigned short us[4]; ushort4 v; } o;
                #pragma unroll
                for (int r = 0; r < 4; r++) o.us[r] = f2bf(acc[jt][dt][r]);
                *reinterpret_cast<ushort4*>(pa + (jt*16+jl)*64 + dt*16 + 4*kg) = o.v;
            }
        }
    }
}

// ---------------------------------------------------------------------------
// K3b: combine the two KV-chunk partials of each heavy q-block, normalize,
// write tws. 2048 tiles; block=256 handles 4 tiles (64 thr/tile).
// ---------------------------------------------------------------------------
__global__ __launch_bounds__(256) void k_reduce(const unsigned short* __restrict__ pacc,
                                                const float* __restrict__ pl,
                                                unsigned short* __restrict__ tws){
    const int g  = blockIdx.x*4 + (threadIdx.x >> 6);   // tile 0..2047
    const int t  = threadIdx.x & 63;
    const int bh = g >> 5, qh = g & 31;
    const int q  = t >> 1;
    const int dbase = (t & 1)*32;
    const size_t slot0 = (size_t)(bh*32 + qh)*2;

    const float inv = 1.0f / (pl[slot0*32 + q] + pl[(slot0+1)*32 + q]);
    const unsigned short* a0 = pacc + slot0*2048 + q*64 + dbase;

    unsigned short* tw = tws + ((size_t)(bh >> 4)*Wn + (qh+32)*32 + q)*E + (bh & 15)*Dh + dbase;
    #pragma unroll
    for (int i = 0; i < 4; i++){
        union { uint4 v; unsigned short us[8]; } r0, r1, o;
        r0.v = *reinterpret_cast<const uint4*>(a0 + i*8);
        r1.v = *reinterpret_cast<const uint4*>(a0 + 2048 + i*8);
        #pragma unroll
        for (int j = 0; j < 8; j++)
            o.us[j] = f2bf((bf2f(r0.us[j]) + bf2f(r1.us[j])) * inv);
        *reinterpret_cast<uint4*>(tw + i*8) = o.v;
    }
}

// ---------------------------------------------------------------------------
// K4: out[b][f][w] = sum_e MT[f][e] * t_ws[b][w][e] + b_d[f]
// 128x128 C-tile per block (4 waves x 64x64); inline-asm loads + counted
// vmcnt ping-pong (same fix as k_attn).
// ---------------------------------------------------------------------------
struct GF { bf16x8 am0, am1, am2, am3, bn0, bn1, bn2, bn3; };

__global__ __launch_bounds__(256)
void k_gemm(const unsigned short* __restrict__ MT,
            const unsigned short* __restrict__ tws,
            const float* __restrict__ bd,
            float* __restrict__ out){
    const int lane = threadIdx.x & 63;
    const int wv   = threadIdx.x >> 6;
    const int jl = lane & 15, kg = lane >> 4;
    const int blk = blockIdx.x;
    const int b  = blk >> 7;          // 128 tiles per batch
    const int t2 = blk & 127;
    const int f0 = (t2 >> 4)*128 + (wv >> 1)*64;
    const int w0 = (t2 & 15)*128 + (wv &  1)*64;

    const char* pA0 = (const char*)MT + (((size_t)(f0 +  0 + jl))*E + kg*8)*2;
    const char* pA1 = (const char*)MT + (((size_t)(f0 + 16 + jl))*E + kg*8)*2;
    const char* pA2 = (const char*)MT + (((size_t)(f0 + 32 + jl))*E + kg*8)*2;
    const char* pA3 = (const char*)MT + (((size_t)(f0 + 48 + jl))*E + kg*8)*2;
    const char* base = (const char*)(tws + (size_t)b*Wn*E);
    const char* pB0 = base + (((size_t)(w0 +  0 + jl))*E + kg*8)*2;
    const char* pB1 = base + (((size_t)(w0 + 16 + jl))*E + kg*8)*2;
    const char* pB2 = base + (((size_t)(w0 + 32 + jl))*E + kg*8)*2;
    const char* pB3 = base + (((size_t)(w0 + 48 + jl))*E + kg*8)*2;

    auto LOAD = [&](GF& g){
        GLOAD(g.am0, pA0, "0");
        GLOAD(g.am1, pA1, "0");
        GLOAD(g.am2, pA2, "0");
        GLOAD(g.am3, pA3, "0");
        GLOAD(g.bn0, pB0, "0");
        GLOAD(g.bn1, pB1, "0");
        GLOAD(g.bn2, pB2, "0");
        GLOAD(g.bn3, pB3, "0");
        pA0 += 64; pA1 += 64; pA2 += 64; pA3 += 64;
        pB0 += 64; pB1 += 64; pB2 += 64; pB3 += 64;
    };

    f32x4 acc[4][4] = {};
    auto compute = [&](const GF& g){
        const bf16x8 am[4] = {g.am0, g.am1, g.am2, g.am3};
        const bf16x8 bn[4] = {g.bn0, g.bn1, g.bn2, g.bn3};
        #pragma unroll
        for (int i = 0; i < 4; i++)
            #pragma unroll
            for (int j = 0; j < 4; j++)
                acc[i][j] = __builtin_amdgcn_mfma_f32_16x16x32_bf16(am[i], bn[j], acc[i][j], 0,0,0);
    };

    {
        GF a, bb;
        LOAD(a);                         // E/32 = 32 steps (even)
        for (int i = 0; i < 15; ++i){
            LOAD(bb); VMWAIT("8"); compute(a);
            LOAD(a);  VMWAIT("8"); compute(bb);
        }
        LOAD(bb); VMWAIT("8"); compute(a);
        VMWAIT("0"); compute(bb);
    }

    #pragma unroll
    for (int i = 0; i < 4; i++){
        float bias[4];
        #pragma unroll
        for (int r = 0; r < 4; r++) bias[r] = bd[f0 + i*16 + 4*kg + r];
        #pragma unroll
        for (int j = 0; j < 4; j++){
            #pragma unroll
            for (int r = 0; r < 4; r++){
                out[((size_t)b*E + f0 + i*16 + 4*kg + r)*Wn + w0 + j*16 + jl]
                    = acc[i][j][r] + bias[r];
            }
        }
    }
}

// ---------------------------------------------------------------------------
extern "C" void kernel_launch(void* const* d_in, const int* in_sizes, int n_in,
                              void* d_out, int out_size, void* d_ws, size_t ws_size,
                              hipStream_t stream) {
    const float* x  = (const float*)d_in[0];   // (B,E,W)
    const float* Md = (const float*)d_in[1];   // (E,E)
    const float* bd = (const float*)d_in[2];   // (E,)
    float* out = (float*)d_out;                // (B,E,W)

    char* ws = (char*)d_ws;
    unsigned short* xT   = (unsigned short*)(ws);                    // 16 MB
    unsigned short* xQ   = (unsigned short*)(ws + (16u << 20));      // 16 MB
    unsigned short* xdi  = (unsigned short*)(ws + (32u << 20));      // 16 MB
    unsigned short* MT   = (unsigned short*)(ws + (48u << 20));      //  2 MB
    unsigned short* tws  = (unsigned short*)(ws + (50u << 20));      // 16 MB
    float*          pl   = (float*)(ws + (66u << 20));               // 512 KB
    unsigned short* pacc = (unsigned short*)(ws + (67u << 20));      // 16 MB

    hipLaunchKernelGGL(k_vint,   dim3(4096), dim3(256), 0, stream, x, xdi);
    hipLaunchKernelGGL(k_xT,     dim3(4096), dim3(256), 0, stream, x, xT, xQ);
    hipLaunchKernelGGL(k_MT,     dim3(512),  dim3(256), 0, stream, Md, MT);
    hipLaunchKernelGGL(k_attn,   dim3(1536), dim3(256), 0, stream, xT, xQ, xdi, tws, pacc, pl);
    hipLaunchKernelGGL(k_reduce, dim3(512),  dim3(256), 0, stream, pacc, pl, tws);
    hipLaunchKernelGGL(k_gemm,   dim3(B*(E/128)*(Wn/128)), dim3(256), 0, stream, MT, tws, bd, out);
}

// Round 11
// 154.675 us; speedup vs baseline: 1.6311x; 1.6204x over previous
//
#include <hip/hip_runtime.h>
#include <hip/hip_bf16.h>

// Problem constants
constexpr int B  = 4;
constexpr int E  = 1024;
constexpr int Wn = 2048;
constexpr int H  = 16;
constexpr int Dh = 64;   // E / H

typedef short bf16x8 __attribute__((ext_vector_type(8)));
typedef float f32x4  __attribute__((ext_vector_type(4)));

__device__ inline unsigned short f2bf(float f){
    unsigned int u = __builtin_bit_cast(unsigned int, f);
    u = (u + 0x7fffu + ((u >> 16) & 1u)) >> 16;   // RNE
    return (unsigned short)u;
}
__device__ inline float bf2f(unsigned short u){
    return __builtin_bit_cast(float, (unsigned int)u << 16);
}
__device__ inline unsigned int pack_bf16_trunc(float lo, float hi){
    return __builtin_amdgcn_perm(__builtin_bit_cast(unsigned int, hi),
                                 __builtin_bit_cast(unsigned int, lo), 0x07060302u);
}
__device__ inline float exp2_fast(float x){ return __builtin_amdgcn_exp2f(x); }

// global -> LDS direct DMA, 16B per lane, dest = wave-uniform base + lane*16
#define GLDS(g, l) __builtin_amdgcn_global_load_lds( \
    (const __attribute__((address_space(1))) void*)(g), \
    (__attribute__((address_space(3))) void*)(l), 16, 0, 0)

// inline-asm load (k_gemm ping-pong, from r10)
#define GLOAD(dst, ptr, OFFSTR) \
    asm volatile("global_load_dwordx4 %0, %1, off offset:" OFFSTR \
                 : "=v"(dst) : "v"(ptr) : "memory")

// ---------------------------------------------------------------------------
// K0: x -> xdi (bf16, columns permuted inside each 32-block for single-MFMA PV)
// ---------------------------------------------------------------------------
__global__ void k_vint(const float* __restrict__ x, unsigned short* __restrict__ xdi){
    int tid = blockIdx.x*256 + threadIdx.x;     // [row(12) | g(8)]
    int g   = tid & 255;
    int row = tid >> 8;
    int kgw = g & 3;
    int kv0 = (g >> 2) << 5;
    const float* src = x + (size_t)row*Wn + kv0 + 4*kgw;
    float4 a = *reinterpret_cast<const float4*>(src);
    float4 b = *reinterpret_cast<const float4*>(src + 16);
    union { unsigned short us[8]; uint4 v; } u;
    u.us[0]=f2bf(a.x); u.us[1]=f2bf(a.y); u.us[2]=f2bf(a.z); u.us[3]=f2bf(a.w);
    u.us[4]=f2bf(b.x); u.us[5]=f2bf(b.y); u.us[6]=f2bf(b.z); u.us[7]=f2bf(b.w);
    *reinterpret_cast<uint4*>(xdi + (size_t)row*Wn + kv0 + 8*kgw) = u.v;
}

// ---------------------------------------------------------------------------
// K1: x -> xT (K operand, unscaled) and xQ (Q operand, scaled E^-0.5*log2e)
// ---------------------------------------------------------------------------
__global__ void k_xT(const float* __restrict__ x, unsigned short* __restrict__ xT,
                     unsigned short* __restrict__ xQ){
    const float qs = 0.03125f * 1.44269504088896340736f;
    int tid = blockIdx.x*256 + threadIdx.x;
    int w   = tid & (Wn-1);
    int dg  = (tid >> 11) & 7;
    int bh  = tid >> 14;
    const float* src = x + ((size_t)bh*Dh + dg*8)*Wn + w;
    union { unsigned short us[8]; uint4 v; } u, uq;
    #pragma unroll
    for (int i = 0; i < 8; i++){
        float f = src[(size_t)i*Wn];
        u.us[i]  = f2bf(f);
        uq.us[i] = f2bf(f * qs);
    }
    size_t off = ((size_t)bh*Wn + w)*Dh + dg*8;
    *reinterpret_cast<uint4*>(xT + off) = u.v;
    *reinterpret_cast<uint4*>(xQ + off) = uq.v;
}

// ---------------------------------------------------------------------------
// K2: M_d -> MT (bf16 transposed)
// ---------------------------------------------------------------------------
__global__ void k_MT(const float* __restrict__ M, unsigned short* __restrict__ MT){
    int tid = blockIdx.x*256 + threadIdx.x;  // [eg(7) | f(10)]
    int f  = tid & (E-1);
    int eg = tid >> 10;
    union { unsigned short us[8]; uint4 v; } u;
    #pragma unroll
    for (int i = 0; i < 8; i++) u.us[i] = f2bf(M[(size_t)(eg*8+i)*E + f]);
    *reinterpret_cast<uint4*>(MT + (size_t)f*E + eg*8) = u.v;
}

// ---------------------------------------------------------------------------
// K3: flash attention with LDS-staged K/V shared by 4 waves (4x fewer global
// requests). Block = 128 queries (4 waves x 32) of one head, one kv chunk.
// Stages of 64 keys: K tile [64 keys][128B] + V tile [64 d][128B] in LDS,
// double-buffered (32KB), loaded via global_load_lds with pre-swizzled
// SOURCE addresses (c16 ^= row&7) so swizzled ds_read_b128 is conflict-free
// (rule #21: linear dest + inverse-swz source + swz read).
// 2-phase loop, counted vmcnt(4) keeps next stage in flight across barrier.
// Math unchanged: no max-tracking, exp2(Q-prescaled), single-MFMA PV via xdi,
// l via ones-MFMA. KV-split for balance (24 blocks/head), additive partials.
// ---------------------------------------------------------------------------
__global__ __launch_bounds__(256)
void k_attn(const unsigned short* __restrict__ xT,
            const unsigned short* __restrict__ xQ,
            const unsigned short* __restrict__ xdi,
            unsigned short* __restrict__ tws,
            unsigned short* __restrict__ pacc,
            float* __restrict__ pl){
    __shared__ char Klds[2*8192];
    __shared__ char Vlds[2*8192];

    const int lane = threadIdx.x & 63;
    const int wv   = threadIdx.x >> 6;
    const int jl = lane & 15, kg = lane >> 4;
    const int sw = jl & 7;

    const int p   = blockIdx.x;
    const int xcd = p & 7;
    const int i   = p >> 3;          // 0..191
    const int hh  = i / 24;          // 0..7
    const int j   = i % 24;          // 0..23
    const int bh  = xcd*8 + hh;      // head 0..63 (heads pinned per XCD)

    int sb, kvb, kve, half; bool heavy;
    if (j < 8){                                    // heavy chunk0
        sb = 8 + j; kvb = 0; kve = 1024; heavy = true; half = 0;
    } else {
        int g = 7 - ((j - 8) >> 1);                // 7..0 descending work
        if (((j - 8) & 1) == 0){                   // heavy chunk1 (has diag)
            sb = 8 + g; kvb = 1024; kve = (sb+1)*128; heavy = true;  half = 1;
        } else {                                   // light (full, has diag)
            sb = g;     kvb = 0;    kve = (sb+1)*128; heavy = false; half = 0;
        }
    }
    const int q0w = sb*128 + wv*32;                // this wave's query base
    const int nst = (kve - kvb) >> 6;              // 64-key stages (>=2)

    // Q fragments (held across the loop)
    const bf16x8* xQr = reinterpret_cast<const bf16x8*>(xQ + (size_t)bh*Wn*Dh);
    bf16x8 bq[2][2];
    #pragma unroll
    for (int jt = 0; jt < 2; jt++){
        bq[jt][0] = xQr[(q0w + jt*16 + jl)*8 + kg];
        bq[jt][1] = xQr[(q0w + jt*16 + jl)*8 + 4 + kg];
    }
    union { bf16x8 v; unsigned short us[8]; } ones;
    #pragma unroll
    for (int i2 = 0; i2 < 8; i2++) ones.us[i2] = 0x3F80;

    f32x4 acc[2][4] = {};
    f32x4 accl[2] = {};

    // ---- staging geometry: each wave DMAs 8 rows per instruction (1KB),
    // 2 K instrs + 2 V instrs per 64-key stage. Source col pre-swizzled.
    const char* Kg = (const char*)xT  + (size_t)bh*Wn*128;      // key rows, 128B
    const char* Vg = (const char*)xdi + (size_t)bh*Dh*(Wn*2);   // d rows, 4KB
    const int rloc = 8*wv + (lane >> 3);           // 0..31 (row within half-tile)
    const int ksw  = ((lane & 7) ^ (rloc & 7))*16; // swizzled 16B col offset

    auto STAGE = [&](int buf, int kvT){
        char* Kb = Klds + buf*8192;
        char* Vb = Vlds + buf*8192;
        const char* kg0 = Kg + (size_t)(kvT + rloc)*128 + ksw;
        const char* vg0 = Vg + (size_t)rloc*(Wn*2) + kvT*2 + ksw;
        GLDS(kg0,             Kb + wv*1024);
        GLDS(kg0 + 32*128,    Kb + 4096 + wv*1024);
        GLDS(vg0,             Vb + wv*1024);
        GLDS(vg0 + (size_t)32*(Wn*2), Vb + 4096 + wv*1024);
    };

    auto computeS = [&](int buf, int s, bool dg){
        const char* Kb = Klds + buf*8192;
        const char* Vb = Vlds + buf*8192;
        const int r0 = s*32 + jl, r1 = r0 + 16;
        bf16x8 k0a = *(const bf16x8*)(Kb + r0*128 + ((kg    )^sw)*16);
        bf16x8 k0b = *(const bf16x8*)(Kb + r0*128 + ((kg + 4)^sw)*16);
        bf16x8 k1a = *(const bf16x8*)(Kb + r1*128 + ((kg    )^sw)*16);
        bf16x8 k1b = *(const bf16x8*)(Kb + r1*128 + ((kg + 4)^sw)*16);
        const int vsw = ((s*4 + kg)^sw)*16;
        bf16x8 v0 = *(const bf16x8*)(Vb + (     jl)*128 + vsw);
        bf16x8 v1 = *(const bf16x8*)(Vb + (16 + jl)*128 + vsw);
        bf16x8 v2 = *(const bf16x8*)(Vb + (32 + jl)*128 + vsw);
        bf16x8 v3 = *(const bf16x8*)(Vb + (48 + jl)*128 + vsw);

        #pragma unroll
        for (int jt = 0; jt < 2; jt++){
            f32x4 s0 = {0,0,0,0}, s1 = {0,0,0,0};
            s0 = __builtin_amdgcn_mfma_f32_16x16x32_bf16(k0a, bq[jt][0], s0, 0,0,0);
            s0 = __builtin_amdgcn_mfma_f32_16x16x32_bf16(k0b, bq[jt][1], s0, 0,0,0);
            s1 = __builtin_amdgcn_mfma_f32_16x16x32_bf16(k1a, bq[jt][0], s1, 0,0,0);
            s1 = __builtin_amdgcn_mfma_f32_16x16x32_bf16(k1b, bq[jt][1], s1, 0,0,0);

            union { bf16x8 v; unsigned int w[4]; } bp;
            if (!dg){
                bp.w[0] = pack_bf16_trunc(exp2_fast(s0[0]), exp2_fast(s0[1]));
                bp.w[1] = pack_bf16_trunc(exp2_fast(s0[2]), exp2_fast(s0[3]));
                bp.w[2] = pack_bf16_trunc(exp2_fast(s1[0]), exp2_fast(s1[1]));
                bp.w[3] = pack_bf16_trunc(exp2_fast(s1[2]), exp2_fast(s1[3]));
            } else {
                const int lim = 16*jt + jl;
                float pp[8];
                #pragma unroll
                for (int r = 0; r < 4; r++){
                    int c = 4*kg + r;
                    pp[r]   = (c      <= lim) ? exp2_fast(s0[r]) : 0.f;
                    pp[4+r] = (c + 16 <= lim) ? exp2_fast(s1[r]) : 0.f;
                }
                bp.w[0] = pack_bf16_trunc(pp[0], pp[1]);
                bp.w[1] = pack_bf16_trunc(pp[2], pp[3]);
                bp.w[2] = pack_bf16_trunc(pp[4], pp[5]);
                bp.w[3] = pack_bf16_trunc(pp[6], pp[7]);
            }
            accl[jt] = __builtin_amdgcn_mfma_f32_16x16x32_bf16(ones.v, bp.v, accl[jt], 0,0,0);
            acc[jt][0] = __builtin_amdgcn_mfma_f32_16x16x32_bf16(v0, bp.v, acc[jt][0], 0,0,0);
            acc[jt][1] = __builtin_amdgcn_mfma_f32_16x16x32_bf16(v1, bp.v, acc[jt][1], 0,0,0);
            acc[jt][2] = __builtin_amdgcn_mfma_f32_16x16x32_bf16(v2, bp.v, acc[jt][2], 0,0,0);
            acc[jt][3] = __builtin_amdgcn_mfma_f32_16x16x32_bf16(v3, bp.v, acc[jt][3], 0,0,0);
        }
    };

    // ---- 2-phase pipelined stage loop
    STAGE(0, kvb);
    for (int t = 0; t < nst; ++t){
        const int kvT = kvb + 64*t;
        if (t + 1 < nst){
            STAGE((t+1)&1, kvT + 64);
            asm volatile("s_waitcnt vmcnt(4)" ::: "memory");  // stage t done
        } else {
            asm volatile("s_waitcnt vmcnt(0)" ::: "memory");
        }
        __builtin_amdgcn_s_barrier();                          // all stages t done
        __builtin_amdgcn_sched_barrier(0);
        #pragma unroll
        for (int s = 0; s < 2; ++s){
            const int kv = kvT + 32*s;
            if (kv > q0w) continue;          // wave-uniform skip past diagonal
            computeS(t & 1, s, kv == q0w);
        }
        asm volatile("s_waitcnt lgkmcnt(0)" ::: "memory");     // reads drained
        __builtin_amdgcn_sched_barrier(0);
        __builtin_amdgcn_s_barrier();                          // safe to overwrite
    }

    if (!heavy){
        // ---- light epilogue: normalize (accl holds column sums), write tws
        #pragma unroll
        for (int jt = 0; jt < 2; jt++){
            const float inv = 1.0f / accl[jt][0];
            unsigned short* trow = tws + ((size_t)(bh >> 4)*Wn + q0w + jt*16 + jl)*E + (bh & 15)*Dh;
            #pragma unroll
            for (int dt = 0; dt < 4; dt++){
                union { unsigned short us[4]; ushort4 v; } o;
                #pragma unroll
                for (int r = 0; r < 4; r++) o.us[r] = f2bf(acc[jt][dt][r] * inv);
                *reinterpret_cast<ushort4*>(trow + dt*16 + 4*kg) = o.v;
            }
        }
    } else {
        // ---- heavy epilogue: bf16 acc partial + f32 l partial
        const int qh = sb - 8;
        const size_t slot = (size_t)(bh*8 + qh)*2 + half;
        if (kg == 0){
            pl[slot*128 + wv*32 + jl]      = accl[0][0];
            pl[slot*128 + wv*32 + 16 + jl] = accl[1][0];
        }
        unsigned short* pa = pacc + slot*8192;
        #pragma unroll
        for (int jt = 0; jt < 2; jt++){
            #pragma unroll
            for (int dt = 0; dt < 4; dt++){
                union { unsigned short us[4]; ushort4 v; } o;
                #pragma unroll
                for (int r = 0; r < 4; r++) o.us[r] = f2bf(acc[jt][dt][r]);
                *reinterpret_cast<ushort4*>(pa + (wv*32 + jt*16 + jl)*64 + dt*16 + 4*kg) = o.v;
            }
        }
    }
}

// ---------------------------------------------------------------------------
// K3b: combine the two KV-chunk partials of each heavy 128-query super-block,
// normalize, write tws. 512 blocks, one (bh, qh) tile each.
// ---------------------------------------------------------------------------
__global__ __launch_bounds__(256) void k_reduce(const unsigned short* __restrict__ pacc,
                                                const float* __restrict__ pl,
                                                unsigned short* __restrict__ tws){
    const int g  = blockIdx.x;            // bh*8 + qh
    const int bh = g >> 3, qh = g & 7;
    const int t  = threadIdx.x;
    const int q  = t >> 1;                // 0..127
    const int dbase = (t & 1)*32;
    const size_t slot0 = (size_t)g*2;

    const float inv = 1.0f / (pl[slot0*128 + q] + pl[slot0*128 + 128 + q]);
    const unsigned short* a0 = pacc + slot0*8192 + q*64 + dbase;

    unsigned short* tw = tws + ((size_t)(bh >> 4)*Wn + 1024 + qh*128 + q)*E + (bh & 15)*Dh + dbase;
    #pragma unroll
    for (int i = 0; i < 4; i++){
        union { uint4 v; unsigned short us[8]; } r0, r1, o;
        r0.v = *reinterpret_cast<const uint4*>(a0 + i*8);
        r1.v = *reinterpret_cast<const uint4*>(a0 + 8192 + i*8);
        #pragma unroll
        for (int jj = 0; jj < 8; jj++)
            o.us[jj] = f2bf((bf2f(r0.us[jj]) + bf2f(r1.us[jj])) * inv);
        *reinterpret_cast<uint4*>(tw + i*8) = o.v;
    }
}

// ---------------------------------------------------------------------------
// K4: out[b][f][w] = sum_e MT[f][e] * t_ws[b][w][e] + b_d[f]
// 128x128 C-tile per block (4 waves x 64x64); inline-asm loads + counted
// vmcnt ping-pong (r10).
// ---------------------------------------------------------------------------
struct GF { bf16x8 am0, am1, am2, am3, bn0, bn1, bn2, bn3; };

__global__ __launch_bounds__(256)
void k_gemm(const unsigned short* __restrict__ MT,
            const unsigned short* __restrict__ tws,
            const float* __restrict__ bd,
            float* __restrict__ out){
    const int lane = threadIdx.x & 63;
    const int wv   = threadIdx.x >> 6;
    const int jl = lane & 15, kg = lane >> 4;
    const int blk = blockIdx.x;
    const int b  = blk >> 7;          // 128 tiles per batch
    const int t2 = blk & 127;
    const int f0 = (t2 >> 4)*128 + (wv >> 1)*64;
    const int w0 = (t2 & 15)*128 + (wv &  1)*64;

    const char* pA0 = (const char*)MT + (((size_t)(f0 +  0 + jl))*E + kg*8)*2;
    const char* pA1 = (const char*)MT + (((size_t)(f0 + 16 + jl))*E + kg*8)*2;
    const char* pA2 = (const char*)MT + (((size_t)(f0 + 32 + jl))*E + kg*8)*2;
    const char* pA3 = (const char*)MT + (((size_t)(f0 + 48 + jl))*E + kg*8)*2;
    const char* base = (const char*)(tws + (size_t)b*Wn*E);
    const char* pB0 = base + (((size_t)(w0 +  0 + jl))*E + kg*8)*2;
    const char* pB1 = base + (((size_t)(w0 + 16 + jl))*E + kg*8)*2;
    const char* pB2 = base + (((size_t)(w0 + 32 + jl))*E + kg*8)*2;
    const char* pB3 = base + (((size_t)(w0 + 48 + jl))*E + kg*8)*2;

    auto LOAD = [&](GF& g){
        GLOAD(g.am0, pA0, "0");
        GLOAD(g.am1, pA1, "0");
        GLOAD(g.am2, pA2, "0");
        GLOAD(g.am3, pA3, "0");
        GLOAD(g.bn0, pB0, "0");
        GLOAD(g.bn1, pB1, "0");
        GLOAD(g.bn2, pB2, "0");
        GLOAD(g.bn3, pB3, "0");
        pA0 += 64; pA1 += 64; pA2 += 64; pA3 += 64;
        pB0 += 64; pB1 += 64; pB2 += 64; pB3 += 64;
    };

    f32x4 acc[4][4] = {};
    auto compute = [&](const GF& g){
        const bf16x8 am[4] = {g.am0, g.am1, g.am2, g.am3};
        const bf16x8 bn[4] = {g.bn0, g.bn1, g.bn2, g.bn3};
        #pragma unroll
        for (int i = 0; i < 4; i++)
            #pragma unroll
            for (int j = 0; j < 4; j++)
                acc[i][j] = __builtin_amdgcn_mfma_f32_16x16x32_bf16(am[i], bn[j], acc[i][j], 0,0,0);
    };

    {
        GF a, bb;
        LOAD(a);                         // E/32 = 32 steps (even)
        for (int i = 0; i < 15; ++i){
            LOAD(bb);
            asm volatile("s_waitcnt vmcnt(8)" ::: "memory");
            __builtin_amdgcn_sched_barrier(0);
            compute(a);
            LOAD(a);
            asm volatile("s_waitcnt vmcnt(8)" ::: "memory");
            __builtin_amdgcn_sched_barrier(0);
            compute(bb);
        }
        LOAD(bb);
        asm volatile("s_waitcnt vmcnt(8)" ::: "memory");
        __builtin_amdgcn_sched_barrier(0);
        compute(a);
        asm volatile("s_waitcnt vmcnt(0)" ::: "memory");
        __builtin_amdgcn_sched_barrier(0);
        compute(bb);
    }

    #pragma unroll
    for (int i = 0; i < 4; i++){
        float bias[4];
        #pragma unroll
        for (int r = 0; r < 4; r++) bias[r] = bd[f0 + i*16 + 4*kg + r];
        #pragma unroll
        for (int j = 0; j < 4; j++){
            #pragma unroll
            for (int r = 0; r < 4; r++){
                out[((size_t)b*E + f0 + i*16 + 4*kg + r)*Wn + w0 + j*16 + jl]
                    = acc[i][j][r] + bias[r];
            }
        }
    }
}

// ---------------------------------------------------------------------------
extern "C" void kernel_launch(void* const* d_in, const int* in_sizes, int n_in,
                              void* d_out, int out_size, void* d_ws, size_t ws_size,
                              hipStream_t stream) {
    const float* x  = (const float*)d_in[0];   // (B,E,W)
    const float* Md = (const float*)d_in[1];   // (E,E)
    const float* bd = (const float*)d_in[2];   // (E,)
    float* out = (float*)d_out;                // (B,E,W)

    char* ws = (char*)d_ws;
    unsigned short* xT   = (unsigned short*)(ws);                    // 16 MB
    unsigned short* xQ   = (unsigned short*)(ws + (16u << 20));      // 16 MB
    unsigned short* xdi  = (unsigned short*)(ws + (32u << 20));      // 16 MB
    unsigned short* MT   = (unsigned short*)(ws + (48u << 20));      //  2 MB
    unsigned short* tws  = (unsigned short*)(ws + (50u << 20));      // 16 MB
    float*          pl   = (float*)(ws + (66u << 20));               // 512 KB
    unsigned short* pacc = (unsigned short*)(ws + (67u << 20));      // 16 MB

    hipLaunchKernelGGL(k_vint,   dim3(4096), dim3(256), 0, stream, x, xdi);
    hipLaunchKernelGGL(k_xT,     dim3(4096), dim3(256), 0, stream, x, xT, xQ);
    hipLaunchKernelGGL(k_MT,     dim3(512),  dim3(256), 0, stream, Md, MT);
    hipLaunchKernelGGL(k_attn,   dim3(1536), dim3(256), 0, stream, xT, xQ, xdi, tws, pacc, pl);
    hipLaunchKernelGGL(k_reduce, dim3(512),  dim3(256), 0, stream, pacc, pl, tws);
    hipLaunchKernelGGL(k_gemm,   dim3(B*(E/128)*(Wn/128)), dim3(256), 0, stream, MT, tws, bd, out);
}

// Round 12
// 118.260 us; speedup vs baseline: 2.1334x; 1.3079x over previous
//
#include <hip/hip_runtime.h>
#include <hip/hip_bf16.h>

// Problem constants
constexpr int B  = 4;
constexpr int E  = 1024;
constexpr int Wn = 2048;
constexpr int H  = 16;
constexpr int Dh = 64;   // E / H

typedef short bf16x8 __attribute__((ext_vector_type(8)));
typedef float f32x4  __attribute__((ext_vector_type(4)));

__device__ inline unsigned short f2bf(float f){
    unsigned int u = __builtin_bit_cast(unsigned int, f);
    u = (u + 0x7fffu + ((u >> 16) & 1u)) >> 16;   // RNE
    return (unsigned short)u;
}
__device__ inline float bf2f(unsigned short u){
    return __builtin_bit_cast(float, (unsigned int)u << 16);
}
__device__ inline unsigned int pack_bf16_trunc(float lo, float hi){
    return __builtin_amdgcn_perm(__builtin_bit_cast(unsigned int, hi),
                                 __builtin_bit_cast(unsigned int, lo), 0x07060302u);
}
__device__ inline float exp2_fast(float x){ return __builtin_amdgcn_exp2f(x); }

// global -> LDS direct DMA, 16B per lane, dest = wave-uniform base + lane*16
#define GLDS(g, l) __builtin_amdgcn_global_load_lds( \
    (const __attribute__((address_space(1))) void*)(g), \
    (__attribute__((address_space(3))) void*)(l), 16, 0, 0)

// ---------------------------------------------------------------------------
// K0: x -> xdi (bf16, columns permuted inside each 32-block for single-MFMA PV)
// ---------------------------------------------------------------------------
__global__ void k_vint(const float* __restrict__ x, unsigned short* __restrict__ xdi){
    int tid = blockIdx.x*256 + threadIdx.x;     // [row(12) | g(8)]
    int g   = tid & 255;
    int row = tid >> 8;
    int kgw = g & 3;
    int kv0 = (g >> 2) << 5;
    const float* src = x + (size_t)row*Wn + kv0 + 4*kgw;
    float4 a = *reinterpret_cast<const float4*>(src);
    float4 b = *reinterpret_cast<const float4*>(src + 16);
    union { unsigned short us[8]; uint4 v; } u;
    u.us[0]=f2bf(a.x); u.us[1]=f2bf(a.y); u.us[2]=f2bf(a.z); u.us[3]=f2bf(a.w);
    u.us[4]=f2bf(b.x); u.us[5]=f2bf(b.y); u.us[6]=f2bf(b.z); u.us[7]=f2bf(b.w);
    *reinterpret_cast<uint4*>(xdi + (size_t)row*Wn + kv0 + 8*kgw) = u.v;
}

// ---------------------------------------------------------------------------
// K1: x -> xT (K operand, unscaled) and xQ (Q operand, scaled E^-0.5*log2e)
// ---------------------------------------------------------------------------
__global__ void k_xT(const float* __restrict__ x, unsigned short* __restrict__ xT,
                     unsigned short* __restrict__ xQ){
    const float qs = 0.03125f * 1.44269504088896340736f;
    int tid = blockIdx.x*256 + threadIdx.x;
    int w   = tid & (Wn-1);
    int dg  = (tid >> 11) & 7;
    int bh  = tid >> 14;
    const float* src = x + ((size_t)bh*Dh + dg*8)*Wn + w;
    union { unsigned short us[8]; uint4 v; } u, uq;
    #pragma unroll
    for (int i = 0; i < 8; i++){
        float f = src[(size_t)i*Wn];
        u.us[i]  = f2bf(f);
        uq.us[i] = f2bf(f * qs);
    }
    size_t off = ((size_t)bh*Wn + w)*Dh + dg*8;
    *reinterpret_cast<uint4*>(xT + off) = u.v;
    *reinterpret_cast<uint4*>(xQ + off) = uq.v;
}

// ---------------------------------------------------------------------------
// K2: M_d -> MT (bf16 transposed)
// ---------------------------------------------------------------------------
__global__ void k_MT(const float* __restrict__ M, unsigned short* __restrict__ MT){
    int tid = blockIdx.x*256 + threadIdx.x;  // [eg(7) | f(10)]
    int f  = tid & (E-1);
    int eg = tid >> 10;
    union { unsigned short us[8]; uint4 v; } u;
    #pragma unroll
    for (int i = 0; i < 8; i++) u.us[i] = f2bf(M[(size_t)(eg*8+i)*E + f]);
    *reinterpret_cast<uint4*>(MT + (size_t)f*E + eg*8) = u.v;
}

// ---------------------------------------------------------------------------
// K3: flash attention with LDS-staged K/V shared by 4 waves (r11, unchanged).
// ---------------------------------------------------------------------------
__global__ __launch_bounds__(256)
void k_attn(const unsigned short* __restrict__ xT,
            const unsigned short* __restrict__ xQ,
            const unsigned short* __restrict__ xdi,
            unsigned short* __restrict__ tws,
            unsigned short* __restrict__ pacc,
            float* __restrict__ pl){
    __shared__ char Klds[2*8192];
    __shared__ char Vlds[2*8192];

    const int lane = threadIdx.x & 63;
    const int wv   = threadIdx.x >> 6;
    const int jl = lane & 15, kg = lane >> 4;
    const int sw = jl & 7;

    const int p   = blockIdx.x;
    const int xcd = p & 7;
    const int i   = p >> 3;          // 0..191
    const int hh  = i / 24;          // 0..7
    const int j   = i % 24;          // 0..23
    const int bh  = xcd*8 + hh;      // head 0..63 (heads pinned per XCD)

    int sb, kvb, kve, half; bool heavy;
    if (j < 8){                                    // heavy chunk0
        sb = 8 + j; kvb = 0; kve = 1024; heavy = true; half = 0;
    } else {
        int g = 7 - ((j - 8) >> 1);                // 7..0 descending work
        if (((j - 8) & 1) == 0){                   // heavy chunk1 (has diag)
            sb = 8 + g; kvb = 1024; kve = (sb+1)*128; heavy = true;  half = 1;
        } else {                                   // light (full, has diag)
            sb = g;     kvb = 0;    kve = (sb+1)*128; heavy = false; half = 0;
        }
    }
    const int q0w = sb*128 + wv*32;                // this wave's query base
    const int nst = (kve - kvb) >> 6;              // 64-key stages (>=2)

    const bf16x8* xQr = reinterpret_cast<const bf16x8*>(xQ + (size_t)bh*Wn*Dh);
    bf16x8 bq[2][2];
    #pragma unroll
    for (int jt = 0; jt < 2; jt++){
        bq[jt][0] = xQr[(q0w + jt*16 + jl)*8 + kg];
        bq[jt][1] = xQr[(q0w + jt*16 + jl)*8 + 4 + kg];
    }
    union { bf16x8 v; unsigned short us[8]; } ones;
    #pragma unroll
    for (int i2 = 0; i2 < 8; i2++) ones.us[i2] = 0x3F80;

    f32x4 acc[2][4] = {};
    f32x4 accl[2] = {};

    const char* Kg = (const char*)xT  + (size_t)bh*Wn*128;      // key rows, 128B
    const char* Vg = (const char*)xdi + (size_t)bh*Dh*(Wn*2);   // d rows, 4KB
    const int rloc = 8*wv + (lane >> 3);           // 0..31
    const int ksw  = ((lane & 7) ^ (rloc & 7))*16; // swizzled 16B col offset

    auto STAGE = [&](int buf, int kvT){
        char* Kb = Klds + buf*8192;
        char* Vb = Vlds + buf*8192;
        const char* kg0 = Kg + (size_t)(kvT + rloc)*128 + ksw;
        const char* vg0 = Vg + (size_t)rloc*(Wn*2) + kvT*2 + ksw;
        GLDS(kg0,             Kb + wv*1024);
        GLDS(kg0 + 32*128,    Kb + 4096 + wv*1024);
        GLDS(vg0,             Vb + wv*1024);
        GLDS(vg0 + (size_t)32*(Wn*2), Vb + 4096 + wv*1024);
    };

    auto computeS = [&](int buf, int s, bool dg){
        const char* Kb = Klds + buf*8192;
        const char* Vb = Vlds + buf*8192;
        const int r0 = s*32 + jl, r1 = r0 + 16;
        bf16x8 k0a = *(const bf16x8*)(Kb + r0*128 + ((kg    )^sw)*16);
        bf16x8 k0b = *(const bf16x8*)(Kb + r0*128 + ((kg + 4)^sw)*16);
        bf16x8 k1a = *(const bf16x8*)(Kb + r1*128 + ((kg    )^sw)*16);
        bf16x8 k1b = *(const bf16x8*)(Kb + r1*128 + ((kg + 4)^sw)*16);
        const int vsw = ((s*4 + kg)^sw)*16;
        bf16x8 v0 = *(const bf16x8*)(Vb + (     jl)*128 + vsw);
        bf16x8 v1 = *(const bf16x8*)(Vb + (16 + jl)*128 + vsw);
        bf16x8 v2 = *(const bf16x8*)(Vb + (32 + jl)*128 + vsw);
        bf16x8 v3 = *(const bf16x8*)(Vb + (48 + jl)*128 + vsw);

        #pragma unroll
        for (int jt = 0; jt < 2; jt++){
            f32x4 s0 = {0,0,0,0}, s1 = {0,0,0,0};
            s0 = __builtin_amdgcn_mfma_f32_16x16x32_bf16(k0a, bq[jt][0], s0, 0,0,0);
            s0 = __builtin_amdgcn_mfma_f32_16x16x32_bf16(k0b, bq[jt][1], s0, 0,0,0);
            s1 = __builtin_amdgcn_mfma_f32_16x16x32_bf16(k1a, bq[jt][0], s1, 0,0,0);
            s1 = __builtin_amdgcn_mfma_f32_16x16x32_bf16(k1b, bq[jt][1], s1, 0,0,0);

            union { bf16x8 v; unsigned int w[4]; } bp;
            if (!dg){
                bp.w[0] = pack_bf16_trunc(exp2_fast(s0[0]), exp2_fast(s0[1]));
                bp.w[1] = pack_bf16_trunc(exp2_fast(s0[2]), exp2_fast(s0[3]));
                bp.w[2] = pack_bf16_trunc(exp2_fast(s1[0]), exp2_fast(s1[1]));
                bp.w[3] = pack_bf16_trunc(exp2_fast(s1[2]), exp2_fast(s1[3]));
            } else {
                const int lim = 16*jt + jl;
                float pp[8];
                #pragma unroll
                for (int r = 0; r < 4; r++){
                    int c = 4*kg + r;
                    pp[r]   = (c      <= lim) ? exp2_fast(s0[r]) : 0.f;
                    pp[4+r] = (c + 16 <= lim) ? exp2_fast(s1[r]) : 0.f;
                }
                bp.w[0] = pack_bf16_trunc(pp[0], pp[1]);
                bp.w[1] = pack_bf16_trunc(pp[2], pp[3]);
                bp.w[2] = pack_bf16_trunc(pp[4], pp[5]);
                bp.w[3] = pack_bf16_trunc(pp[6], pp[7]);
            }
            accl[jt] = __builtin_amdgcn_mfma_f32_16x16x32_bf16(ones.v, bp.v, accl[jt], 0,0,0);
            acc[jt][0] = __builtin_amdgcn_mfma_f32_16x16x32_bf16(v0, bp.v, acc[jt][0], 0,0,0);
            acc[jt][1] = __builtin_amdgcn_mfma_f32_16x16x32_bf16(v1, bp.v, acc[jt][1], 0,0,0);
            acc[jt][2] = __builtin_amdgcn_mfma_f32_16x16x32_bf16(v2, bp.v, acc[jt][2], 0,0,0);
            acc[jt][3] = __builtin_amdgcn_mfma_f32_16x16x32_bf16(v3, bp.v, acc[jt][3], 0,0,0);
        }
    };

    STAGE(0, kvb);
    for (int t = 0; t < nst; ++t){
        const int kvT = kvb + 64*t;
        if (t + 1 < nst){
            STAGE((t+1)&1, kvT + 64);
            asm volatile("s_waitcnt vmcnt(4)" ::: "memory");
        } else {
            asm volatile("s_waitcnt vmcnt(0)" ::: "memory");
        }
        __builtin_amdgcn_s_barrier();
        __builtin_amdgcn_sched_barrier(0);
        #pragma unroll
        for (int s = 0; s < 2; ++s){
            const int kv = kvT + 32*s;
            if (kv > q0w) continue;
            computeS(t & 1, s, kv == q0w);
        }
        asm volatile("s_waitcnt lgkmcnt(0)" ::: "memory");
        __builtin_amdgcn_sched_barrier(0);
        __builtin_amdgcn_s_barrier();
    }

    if (!heavy){
        #pragma unroll
        for (int jt = 0; jt < 2; jt++){
            const float inv = 1.0f / accl[jt][0];
            unsigned short* trow = tws + ((size_t)(bh >> 4)*Wn + q0w + jt*16 + jl)*E + (bh & 15)*Dh;
            #pragma unroll
            for (int dt = 0; dt < 4; dt++){
                union { unsigned short us[4]; ushort4 v; } o;
                #pragma unroll
                for (int r = 0; r < 4; r++) o.us[r] = f2bf(acc[jt][dt][r] * inv);
                *reinterpret_cast<ushort4*>(trow + dt*16 + 4*kg) = o.v;
            }
        }
    } else {
        const int qh = sb - 8;
        const size_t slot = (size_t)(bh*8 + qh)*2 + half;
        if (kg == 0){
            pl[slot*128 + wv*32 + jl]      = accl[0][0];
            pl[slot*128 + wv*32 + 16 + jl] = accl[1][0];
        }
        unsigned short* pa = pacc + slot*8192;
        #pragma unroll
        for (int jt = 0; jt < 2; jt++){
            #pragma unroll
            for (int dt = 0; dt < 4; dt++){
                union { unsigned short us[4]; ushort4 v; } o;
                #pragma unroll
                for (int r = 0; r < 4; r++) o.us[r] = f2bf(acc[jt][dt][r]);
                *reinterpret_cast<ushort4*>(pa + (wv*32 + jt*16 + jl)*64 + dt*16 + 4*kg) = o.v;
            }
        }
    }
}

// ---------------------------------------------------------------------------
// K3b: combine the two KV-chunk partials (r11, unchanged).
// ---------------------------------------------------------------------------
__global__ __launch_bounds__(256) void k_reduce(const unsigned short* __restrict__ pacc,
                                                const float* __restrict__ pl,
                                                unsigned short* __restrict__ tws){
    const int g  = blockIdx.x;            // bh*8 + qh
    const int bh = g >> 3, qh = g & 7;
    const int t  = threadIdx.x;
    const int q  = t >> 1;                // 0..127
    const int dbase = (t & 1)*32;
    const size_t slot0 = (size_t)g*2;

    const float inv = 1.0f / (pl[slot0*128 + q] + pl[slot0*128 + 128 + q]);
    const unsigned short* a0 = pacc + slot0*8192 + q*64 + dbase;

    unsigned short* tw = tws + ((size_t)(bh >> 4)*Wn + 1024 + qh*128 + q)*E + (bh & 15)*Dh + dbase;
    #pragma unroll
    for (int i = 0; i < 4; i++){
        union { uint4 v; unsigned short us[8]; } r0, r1, o;
        r0.v = *reinterpret_cast<const uint4*>(a0 + i*8);
        r1.v = *reinterpret_cast<const uint4*>(a0 + 8192 + i*8);
        #pragma unroll
        for (int jj = 0; jj < 8; jj++)
            o.us[jj] = f2bf((bf2f(r0.us[jj]) + bf2f(r1.us[jj])) * inv);
        *reinterpret_cast<uint4*>(tw + i*8) = o.v;
    }
}

// ---------------------------------------------------------------------------
// K4: out[b][f][w] = sum_e MT[f][e] * t_ws[b][w][e] + b_d[f]
// Round-12: LDS-staged GEMM (same cure as k_attn). 128x128 C-tile, K-stage
// 64e: A-tile 128x128B + B-tile 128x128B staged via global_load_lds with
// pre-swizzled source (rule #21), double-buffered (64KB). Counted vmcnt(8)
// keeps next stage in flight across the barrier. Per stage/wave: 16 swizzled
// ds_read_b128 + 32 MFMA. Bijective XCD swizzle (512 blocks % 8 == 0).
// ---------------------------------------------------------------------------
__global__ __launch_bounds__(256)
void k_gemm(const unsigned short* __restrict__ MT,
            const unsigned short* __restrict__ tws,
            const float* __restrict__ bd,
            float* __restrict__ out){
    __shared__ char Alds[2*16384];
    __shared__ char Blds[2*16384];

    const int lane = threadIdx.x & 63;
    const int wv   = threadIdx.x >> 6;
    const int jl = lane & 15, kg = lane >> 4;
    const int sw = jl & 7;

    const int p   = blockIdx.x;
    const int blk = (p & 7)*64 + (p >> 3);   // XCD-contiguous logical block
    const int b  = blk >> 7;                 // 128 tiles per batch
    const int t2 = blk & 127;
    const int fblk = (t2 >> 4)*128;
    const int wblk = (t2 & 15)*128;
    const int f0 = fblk + (wv >> 1)*64;
    const int w0 = wblk + (wv &  1)*64;

    const char* Ag = (const char*)MT + (size_t)fblk*E*2;
    const char* Bg = (const char*)tws + ((size_t)b*Wn + wblk)*E*2;
    const int rloc = 8*wv + (lane >> 3);            // 0..31
    const int scw  = ((lane & 7) ^ (lane >> 3))*16; // pre-swizzled src col

    auto STAGE = [&](int buf, int e0){
        char* Ab = Alds + buf*16384;
        char* Bb = Blds + buf*16384;
        const char* ag = Ag + (size_t)rloc*(E*2) + e0*2 + scw;
        const char* bg = Bg + (size_t)rloc*(E*2) + e0*2 + scw;
        #pragma unroll
        for (int g = 0; g < 4; ++g){
            GLDS(ag + (size_t)g*32*(E*2), Ab + g*4096 + wv*1024);
            GLDS(bg + (size_t)g*32*(E*2), Bb + g*4096 + wv*1024);
        }
    };

    f32x4 acc[4][4] = {};

    auto COMP = [&](int buf){
        const char* Ab = Alds + buf*16384 + ((wv >> 1)*64)*128;
        const char* Bb = Blds + buf*16384 + ((wv &  1)*64)*128;
        #pragma unroll
        for (int h = 0; h < 2; ++h){
            const int cs = ((h*4 + kg) ^ sw)*16;
            bf16x8 am[4], bn[4];
            #pragma unroll
            for (int i = 0; i < 4; i++) am[i] = *(const bf16x8*)(Ab + (i*16 + jl)*128 + cs);
            #pragma unroll
            for (int j = 0; j < 4; j++) bn[j] = *(const bf16x8*)(Bb + (j*16 + jl)*128 + cs);
            #pragma unroll
            for (int i = 0; i < 4; i++)
                #pragma unroll
                for (int j = 0; j < 4; j++)
                    acc[i][j] = __builtin_amdgcn_mfma_f32_16x16x32_bf16(am[i], bn[j], acc[i][j], 0,0,0);
        }
    };

    STAGE(0, 0);
    for (int t = 0; t < 16; ++t){
        if (t < 15){
            STAGE((t+1)&1, (t+1)*64);
            asm volatile("s_waitcnt vmcnt(8)" ::: "memory");
        } else {
            asm volatile("s_waitcnt vmcnt(0)" ::: "memory");
        }
        __builtin_amdgcn_s_barrier();
        __builtin_amdgcn_sched_barrier(0);
        COMP(t & 1);
        asm volatile("s_waitcnt lgkmcnt(0)" ::: "memory");
        __builtin_amdgcn_sched_barrier(0);
        __builtin_amdgcn_s_barrier();
    }

    #pragma unroll
    for (int i = 0; i < 4; i++){
        float bias[4];
        #pragma unroll
        for (int r = 0; r < 4; r++) bias[r] = bd[f0 + i*16 + 4*kg + r];
        #pragma unroll
        for (int j = 0; j < 4; j++){
            #pragma unroll
            for (int r = 0; r < 4; r++){
                out[((size_t)b*E + f0 + i*16 + 4*kg + r)*Wn + w0 + j*16 + jl]
                    = acc[i][j][r] + bias[r];
            }
        }
    }
}

// ---------------------------------------------------------------------------
extern "C" void kernel_launch(void* const* d_in, const int* in_sizes, int n_in,
                              void* d_out, int out_size, void* d_ws, size_t ws_size,
                              hipStream_t stream) {
    const float* x  = (const float*)d_in[0];   // (B,E,W)
    const float* Md = (const float*)d_in[1];   // (E,E)
    const float* bd = (const float*)d_in[2];   // (E,)
    float* out = (float*)d_out;                // (B,E,W)

    char* ws = (char*)d_ws;
    unsigned short* xT   = (unsigned short*)(ws);                    // 16 MB
    unsigned short* xQ   = (unsigned short*)(ws + (16u << 20));      // 16 MB
    unsigned short* xdi  = (unsigned short*)(ws + (32u << 20));      // 16 MB
    unsigned short* MT   = (unsigned short*)(ws + (48u << 20));      //  2 MB
    unsigned short* tws  = (unsigned short*)(ws + (50u << 20));      // 16 MB
    float*          pl   = (float*)(ws + (66u << 20));               // 512 KB
    unsigned short* pacc = (unsigned short*)(ws + (67u << 20));      // 16 MB

    hipLaunchKernelGGL(k_vint,   dim3(4096), dim3(256), 0, stream, x, xdi);
    hipLaunchKernelGGL(k_xT,     dim3(4096), dim3(256), 0, stream, x, xT, xQ);
    hipLaunchKernelGGL(k_MT,     dim3(512),  dim3(256), 0, stream, Md, MT);
    hipLaunchKernelGGL(k_attn,   dim3(1536), dim3(256), 0, stream, xT, xQ, xdi, tws, pacc, pl);
    hipLaunchKernelGGL(k_reduce, dim3(512),  dim3(256), 0, stream, pacc, pl, tws);
    hipLaunchKernelGGL(k_gemm,   dim3(B*(E/128)*(Wn/128)), dim3(256), 0, stream, MT, tws, bd, out);
}

// Round 13
// 113.841 us; speedup vs baseline: 2.2162x; 1.0388x over previous
//
#include <hip/hip_runtime.h>
#include <hip/hip_bf16.h>

// Problem constants
constexpr int B  = 4;
constexpr int E  = 1024;
constexpr int Wn = 2048;
constexpr int H  = 16;
constexpr int Dh = 64;   // E / H

typedef short bf16x8 __attribute__((ext_vector_type(8)));
typedef float f32x4  __attribute__((ext_vector_type(4)));

__device__ inline unsigned short f2bf(float f){
    unsigned int u = __builtin_bit_cast(unsigned int, f);
    u = (u + 0x7fffu + ((u >> 16) & 1u)) >> 16;   // RNE
    return (unsigned short)u;
}
__device__ inline float bf2f(unsigned short u){
    return __builtin_bit_cast(float, (unsigned int)u << 16);
}
__device__ inline unsigned int pack_bf16_trunc(float lo, float hi){
    return __builtin_amdgcn_perm(__builtin_bit_cast(unsigned int, hi),
                                 __builtin_bit_cast(unsigned int, lo), 0x07060302u);
}
__device__ inline float exp2_fast(float x){ return __builtin_amdgcn_exp2f(x); }
// LDS column swizzle for the prep tile (breaks 32-float group degeneracy)
__device__ inline int SW(int c){ return c ^ (((c >> 5) & 7) << 2); }

// global -> LDS direct DMA, 16B per lane, dest = wave-uniform base + lane*16
#define GLDS(g, l) __builtin_amdgcn_global_load_lds( \
    (const __attribute__((address_space(1))) void*)(g), \
    (__attribute__((address_space(3))) void*)(l), 16, 0, 0)

// Work tables: 40 (sb, chunk) items per head, full 8-stage chunks first.
__device__ __constant__ signed char SBT[40] =
    {3,4,5,6,7,7,8,8,9,9,10,10,11,11,11,12,12,12,13,13,13,14,14,14,15,15,15,15,
     2,6,10,14, 1,5,9,13, 0,4,8,12};
__device__ __constant__ signed char CHT[40] =
    {0,0,0,0,0,1,0,1,0,1,0,1,0,1,2,0,1,2,0,1,2,0,1,2,0,1,2,3,
     0,1,2,3, 0,1,2,3, 0,1,2,3};
__device__ __constant__ signed char BASET[16] =
    {0,1,2,3,4,6,8,10,12,15,18,21,24,28,32,36};   // cumsum of ceil((sb+1)/4)

// ---------------------------------------------------------------------------
// K_prep: x read ONCE -> xS (shared Q/K operand, (B*H, W, 64) bf16, scaled by
// cs = sqrt(2^-5 * log2 e) -- Q.K product then carries the full softmax scale)
// and xdi (V operand, (B,E,W) bf16, columns permuted per 32-block for
// single-MFMA PV). LDS fp32 tile 64x256, stride 257 + column-XOR swizzle.
// Grid: 64 heads x 8 w-segments = 512 blocks, 256 threads.
// ---------------------------------------------------------------------------
__global__ __launch_bounds__(256) void k_prep(const float* __restrict__ x,
                                              unsigned short* __restrict__ xS,
                                              unsigned short* __restrict__ xdi){
    __shared__ float tile[64*257];
    const float cs = 0.2123304349f;   // sqrt(log2(e)/32)
    const int t  = threadIdx.x;
    const int bh = blockIdx.x >> 3;
    const int w0 = (blockIdx.x & 7) << 8;

    // phase 1: coalesced-ish read of 64 rows x 256 cols, swizzled LDS store
    {
        const int r = t >> 2, seg = t & 3;
        const float* src = x + ((size_t)bh*64 + r)*Wn + w0 + seg*64;
        float* dst = tile + r*257;
        #pragma unroll
        for (int i = 0; i < 16; ++i){
            float4 v = *reinterpret_cast<const float4*>(src + i*4);
            int c0 = seg*64 + i*4;
            dst[SW(c0+0)] = v.x; dst[SW(c0+1)] = v.y;
            dst[SW(c0+2)] = v.z; dst[SW(c0+3)] = v.w;
        }
    }
    __syncthreads();

    // phase 2a: xdi (row-major, permuted cols), coalesced 16B writes
    {
        const int kgw = t & 3, g = (t >> 2) & 7, r0 = t >> 5;
        #pragma unroll
        for (int rr = 0; rr < 8; ++rr){
            const int r = r0*8 + rr;
            const float* base = tile + r*257;
            const int c0 = g*32 + 4*kgw;
            union { unsigned short us[8]; uint4 v; } u;
            #pragma unroll
            for (int j2 = 0; j2 < 4; ++j2){
                u.us[j2]   = f2bf(base[SW(c0 + j2)]);
                u.us[4+j2] = f2bf(base[SW(c0 + 16 + j2)]);
            }
            *reinterpret_cast<uint4*>(xdi + ((size_t)bh*64 + r)*Wn + w0 + g*32 + 8*kgw) = u.v;
        }
    }
    // phase 2b: xS (transposed, scaled), 16B per (w, dgroup)
    {
        const int w = t;
        #pragma unroll
        for (int dg = 0; dg < 8; ++dg){
            union { unsigned short us[8]; uint4 v; } u;
            #pragma unroll
            for (int i = 0; i < 8; ++i)
                u.us[i] = f2bf(tile[(dg*8 + i)*257 + SW(w)] * cs);
            *reinterpret_cast<uint4*>(xS + ((size_t)bh*Wn + w0 + w)*64 + dg*8) = u.v;
        }
    }
}

// ---------------------------------------------------------------------------
// K2: M_d -> MT (bf16 transposed)
// ---------------------------------------------------------------------------
__global__ void k_MT(const float* __restrict__ M, unsigned short* __restrict__ MT){
    int tid = blockIdx.x*256 + threadIdx.x;  // [eg(7) | f(10)]
    int f  = tid & (E-1);
    int eg = tid >> 10;
    union { unsigned short us[8]; uint4 v; } u;
    #pragma unroll
    for (int i = 0; i < 8; i++) u.us[i] = f2bf(M[(size_t)(eg*8+i)*E + f]);
    *reinterpret_cast<uint4*>(MT + (size_t)f*E + eg*8) = u.v;
}

// ---------------------------------------------------------------------------
// K3: flash attention, LDS-staged K/V (r12 pipeline), UNIFORM 512-key chunks:
// block = (head, superblock sb, chunk) from tables; 2560 blocks, 2-8 stages
// each (28/40 exactly 8). Every block writes additive (acc, l) partials;
// k_reduce combines 1-4 chunks. Q and K both read from the shared scaled xS.
// ---------------------------------------------------------------------------
__global__ __launch_bounds__(256)
void k_attn(const unsigned short* __restrict__ xS,
            const unsigned short* __restrict__ xdi,
            unsigned short* __restrict__ pacc,
            float* __restrict__ pl){
    __shared__ char Klds[2*8192];
    __shared__ char Vlds[2*8192];

    const int lane = threadIdx.x & 63;
    const int wv   = threadIdx.x >> 6;
    const int jl = lane & 15, kg = lane >> 4;
    const int sw = jl & 7;

    const int p    = blockIdx.x;
    const int xcd  = p & 7;
    const int q    = p >> 3;          // 0..319
    const int hh   = q & 7;
    const int widx = q >> 3;          // 0..39 (ascending = heavy first)
    const int bh   = xcd*8 + hh;      // heads pinned per XCD

    const int sb  = SBT[widx];
    const int ch  = CHT[widx];
    const int nst = min(8, (sb+1)*2 - ch*8);       // 64-key stages (2..8)
    const int kvb = ch*512;
    const bool isLast = (kvb + nst*64 == (sb+1)*128);

    const int q0w = sb*128 + wv*32;                // this wave's query base

    // Q fragments from the shared scaled buffer
    const bf16x8* xSr = reinterpret_cast<const bf16x8*>(xS + (size_t)bh*Wn*Dh);
    bf16x8 bq[2][2];
    #pragma unroll
    for (int jt = 0; jt < 2; jt++){
        bq[jt][0] = xSr[(q0w + jt*16 + jl)*8 + kg];
        bq[jt][1] = xSr[(q0w + jt*16 + jl)*8 + 4 + kg];
    }
    union { bf16x8 v; unsigned short us[8]; } ones;
    #pragma unroll
    for (int i2 = 0; i2 < 8; i2++) ones.us[i2] = 0x3F80;

    f32x4 acc[2][4] = {};
    f32x4 accl[2] = {};

    const char* Kg = (const char*)xS  + (size_t)bh*Wn*128;      // key rows, 128B
    const char* Vg = (const char*)xdi + (size_t)bh*Dh*(Wn*2);   // d rows, 4KB
    const int rloc = 8*wv + (lane >> 3);           // 0..31
    const int ksw  = ((lane & 7) ^ (rloc & 7))*16; // pre-swizzled src col

    auto STAGE = [&](int buf, int kvT){
        char* Kb = Klds + buf*8192;
        char* Vb = Vlds + buf*8192;
        const char* kg0 = Kg + (size_t)(kvT + rloc)*128 + ksw;
        const char* vg0 = Vg + (size_t)rloc*(Wn*2) + kvT*2 + ksw;
        GLDS(kg0,             Kb + wv*1024);
        GLDS(kg0 + 32*128,    Kb + 4096 + wv*1024);
        GLDS(vg0,             Vb + wv*1024);
        GLDS(vg0 + (size_t)32*(Wn*2), Vb + 4096 + wv*1024);
    };

    auto computeS = [&](int buf, int s, bool dg){
        const char* Kb = Klds + buf*8192;
        const char* Vb = Vlds + buf*8192;
        const int r0 = s*32 + jl, r1 = r0 + 16;
        bf16x8 k0a = *(const bf16x8*)(Kb + r0*128 + ((kg    )^sw)*16);
        bf16x8 k0b = *(const bf16x8*)(Kb + r0*128 + ((kg + 4)^sw)*16);
        bf16x8 k1a = *(const bf16x8*)(Kb + r1*128 + ((kg    )^sw)*16);
        bf16x8 k1b = *(const bf16x8*)(Kb + r1*128 + ((kg + 4)^sw)*16);
        const int vsw = ((s*4 + kg)^sw)*16;
        bf16x8 v0 = *(const bf16x8*)(Vb + (     jl)*128 + vsw);
        bf16x8 v1 = *(const bf16x8*)(Vb + (16 + jl)*128 + vsw);
        bf16x8 v2 = *(const bf16x8*)(Vb + (32 + jl)*128 + vsw);
        bf16x8 v3 = *(const bf16x8*)(Vb + (48 + jl)*128 + vsw);

        #pragma unroll
        for (int jt = 0; jt < 2; jt++){
            f32x4 s0 = {0,0,0,0}, s1 = {0,0,0,0};
            s0 = __builtin_amdgcn_mfma_f32_16x16x32_bf16(k0a, bq[jt][0], s0, 0,0,0);
            s0 = __builtin_amdgcn_mfma_f32_16x16x32_bf16(k0b, bq[jt][1], s0, 0,0,0);
            s1 = __builtin_amdgcn_mfma_f32_16x16x32_bf16(k1a, bq[jt][0], s1, 0,0,0);
            s1 = __builtin_amdgcn_mfma_f32_16x16x32_bf16(k1b, bq[jt][1], s1, 0,0,0);

            union { bf16x8 v; unsigned int w[4]; } bp;
            if (!dg){
                bp.w[0] = pack_bf16_trunc(exp2_fast(s0[0]), exp2_fast(s0[1]));
                bp.w[1] = pack_bf16_trunc(exp2_fast(s0[2]), exp2_fast(s0[3]));
                bp.w[2] = pack_bf16_trunc(exp2_fast(s1[0]), exp2_fast(s1[1]));
                bp.w[3] = pack_bf16_trunc(exp2_fast(s1[2]), exp2_fast(s1[3]));
            } else {
                const int lim = 16*jt + jl;
                float pp[8];
                #pragma unroll
                for (int r = 0; r < 4; r++){
                    int c = 4*kg + r;
                    pp[r]   = (c      <= lim) ? exp2_fast(s0[r]) : 0.f;
                    pp[4+r] = (c + 16 <= lim) ? exp2_fast(s1[r]) : 0.f;
                }
                bp.w[0] = pack_bf16_trunc(pp[0], pp[1]);
                bp.w[1] = pack_bf16_trunc(pp[2], pp[3]);
                bp.w[2] = pack_bf16_trunc(pp[4], pp[5]);
                bp.w[3] = pack_bf16_trunc(pp[6], pp[7]);
            }
            accl[jt] = __builtin_amdgcn_mfma_f32_16x16x32_bf16(ones.v, bp.v, accl[jt], 0,0,0);
            acc[jt][0] = __builtin_amdgcn_mfma_f32_16x16x32_bf16(v0, bp.v, acc[jt][0], 0,0,0);
            acc[jt][1] = __builtin_amdgcn_mfma_f32_16x16x32_bf16(v1, bp.v, acc[jt][1], 0,0,0);
            acc[jt][2] = __builtin_amdgcn_mfma_f32_16x16x32_bf16(v2, bp.v, acc[jt][2], 0,0,0);
            acc[jt][3] = __builtin_amdgcn_mfma_f32_16x16x32_bf16(v3, bp.v, acc[jt][3], 0,0,0);
        }
    };

    STAGE(0, kvb);
    for (int t = 0; t < nst; ++t){
        const int kvT = kvb + 64*t;
        if (t + 1 < nst){
            STAGE((t+1)&1, kvT + 64);
            asm volatile("s_waitcnt vmcnt(4)" ::: "memory");
        } else {
            asm volatile("s_waitcnt vmcnt(0)" ::: "memory");
        }
        __builtin_amdgcn_s_barrier();
        __builtin_amdgcn_sched_barrier(0);
        #pragma unroll
        for (int s = 0; s < 2; ++s){
            const int kv = kvT + 32*s;
            if (kv > q0w) continue;
            computeS(t & 1, s, isLast && (kv == q0w));
        }
        asm volatile("s_waitcnt lgkmcnt(0)" ::: "memory");
        __builtin_amdgcn_sched_barrier(0);
        __builtin_amdgcn_s_barrier();
    }

    // ---- epilogue: always write bf16 acc partial + f32 l partial
    const int slot = bh*40 + BASET[sb] + ch;
    if (kg == 0){
        pl[(size_t)slot*128 + wv*32 + jl]      = accl[0][0];
        pl[(size_t)slot*128 + wv*32 + 16 + jl] = accl[1][0];
    }
    unsigned short* pa = pacc + (size_t)slot*8192;
    #pragma unroll
    for (int jt = 0; jt < 2; jt++){
        #pragma unroll
        for (int dt = 0; dt < 4; dt++){
            union { unsigned short us[4]; ushort4 v; } o;
            #pragma unroll
            for (int r = 0; r < 4; r++) o.us[r] = f2bf(acc[jt][dt][r]);
            *reinterpret_cast<ushort4*>(pa + (wv*32 + jt*16 + jl)*64 + dt*16 + 4*kg) = o.v;
        }
    }
}

// ---------------------------------------------------------------------------
// K3b: combine 1-4 chunk partials per (head, sb), normalize, write tws.
// Grid 1024 = 64 heads x 16 superblocks; 256 threads (q = t>>1, d-half = t&1).
// ---------------------------------------------------------------------------
__global__ __launch_bounds__(256) void k_reduce(const unsigned short* __restrict__ pacc,
                                                const float* __restrict__ pl,
                                                unsigned short* __restrict__ tws){
    const int g  = blockIdx.x;
    const int bh = g >> 4, sb = g & 15;
    const int t  = threadIdx.x;
    const int qq = t >> 1;
    const int db = (t & 1)*32;
    const int nch   = (sb + 4) >> 2;
    const int slot0 = bh*40 + BASET[sb];

    float l = 0.f;
    float a[32];
    #pragma unroll
    for (int i = 0; i < 32; ++i) a[i] = 0.f;
    for (int c = 0; c < nch; ++c){
        l += pl[(size_t)(slot0 + c)*128 + qq];
        const unsigned short* pa = pacc + (size_t)(slot0 + c)*8192 + qq*64 + db;
        #pragma unroll
        for (int i = 0; i < 4; ++i){
            union { uint4 v; unsigned short us[8]; } r0;
            r0.v = *reinterpret_cast<const uint4*>(pa + i*8);
            #pragma unroll
            for (int j2 = 0; j2 < 8; ++j2) a[i*8 + j2] += bf2f(r0.us[j2]);
        }
    }
    const float inv = 1.0f / l;
    unsigned short* tw = tws + ((size_t)(bh >> 4)*Wn + sb*128 + qq)*E + (bh & 15)*Dh + db;
    #pragma unroll
    for (int i = 0; i < 4; ++i){
        union { uint4 v; unsigned short us[8]; } o;
        #pragma unroll
        for (int j2 = 0; j2 < 8; ++j2) o.us[j2] = f2bf(a[i*8 + j2] * inv);
        *reinterpret_cast<uint4*>(tw + i*8) = o.v;
    }
}

// ---------------------------------------------------------------------------
// K4: out[b][f][w] = sum_e MT[f][e] * t_ws[b][w][e] + b_d[f]   (r12, LDS-staged)
// ---------------------------------------------------------------------------
__global__ __launch_bounds__(256)
void k_gemm(const unsigned short* __restrict__ MT,
            const unsigned short* __restrict__ tws,
            const float* __restrict__ bd,
            float* __restrict__ out){
    __shared__ char Alds[2*16384];
    __shared__ char Blds[2*16384];

    const int lane = threadIdx.x & 63;
    const int wv   = threadIdx.x >> 6;
    const int jl = lane & 15, kg = lane >> 4;
    const int sw = jl & 7;

    const int p   = blockIdx.x;
    const int blk = (p & 7)*64 + (p >> 3);   // XCD-contiguous logical block
    const int b  = blk >> 7;
    const int t2 = blk & 127;
    const int fblk = (t2 >> 4)*128;
    const int wblk = (t2 & 15)*128;
    const int f0 = fblk + (wv >> 1)*64;
    const int w0 = wblk + (wv &  1)*64;

    const char* Ag = (const char*)MT + (size_t)fblk*E*2;
    const char* Bg = (const char*)tws + ((size_t)b*Wn + wblk)*E*2;
    const int rloc = 8*wv + (lane >> 3);
    const int scw  = ((lane & 7) ^ (lane >> 3))*16;

    auto STAGE = [&](int buf, int e0){
        char* Ab = Alds + buf*16384;
        char* Bb = Blds + buf*16384;
        const char* ag = Ag + (size_t)rloc*(E*2) + e0*2 + scw;
        const char* bg = Bg + (size_t)rloc*(E*2) + e0*2 + scw;
        #pragma unroll
        for (int g = 0; g < 4; ++g){
            GLDS(ag + (size_t)g*32*(E*2), Ab + g*4096 + wv*1024);
            GLDS(bg + (size_t)g*32*(E*2), Bb + g*4096 + wv*1024);
        }
    };

    f32x4 acc[4][4] = {};

    auto COMP = [&](int buf){
        const char* Ab = Alds + buf*16384 + ((wv >> 1)*64)*128;
        const char* Bb = Blds + buf*16384 + ((wv &  1)*64)*128;
        #pragma unroll
        for (int h = 0; h < 2; ++h){
            const int cs = ((h*4 + kg) ^ sw)*16;
            bf16x8 am[4], bn[4];
            #pragma unroll
            for (int i = 0; i < 4; i++) am[i] = *(const bf16x8*)(Ab + (i*16 + jl)*128 + cs);
            #pragma unroll
            for (int j = 0; j < 4; j++) bn[j] = *(const bf16x8*)(Bb + (j*16 + jl)*128 + cs);
            #pragma unroll
            for (int i = 0; i < 4; i++)
                #pragma unroll
                for (int j = 0; j < 4; j++)
                    acc[i][j] = __builtin_amdgcn_mfma_f32_16x16x32_bf16(am[i], bn[j], acc[i][j], 0,0,0);
        }
    };

    STAGE(0, 0);
    for (int t = 0; t < 16; ++t){
        if (t < 15){
            STAGE((t+1)&1, (t+1)*64);
            asm volatile("s_waitcnt vmcnt(8)" ::: "memory");
        } else {
            asm volatile("s_waitcnt vmcnt(0)" ::: "memory");
        }
        __builtin_amdgcn_s_barrier();
        __builtin_amdgcn_sched_barrier(0);
        COMP(t & 1);
        asm volatile("s_waitcnt lgkmcnt(0)" ::: "memory");
        __builtin_amdgcn_sched_barrier(0);
        __builtin_amdgcn_s_barrier();
    }

    #pragma unroll
    for (int i = 0; i < 4; i++){
        float bias[4];
        #pragma unroll
        for (int r = 0; r < 4; r++) bias[r] = bd[f0 + i*16 + 4*kg + r];
        #pragma unroll
        for (int j = 0; j < 4; j++){
            #pragma unroll
            for (int r = 0; r < 4; r++){
                out[((size_t)b*E + f0 + i*16 + 4*kg + r)*Wn + w0 + j*16 + jl]
                    = acc[i][j][r] + bias[r];
            }
        }
    }
}

// ---------------------------------------------------------------------------
extern "C" void kernel_launch(void* const* d_in, const int* in_sizes, int n_in,
                              void* d_out, int out_size, void* d_ws, size_t ws_size,
                              hipStream_t stream) {
    const float* x  = (const float*)d_in[0];   // (B,E,W)
    const float* Md = (const float*)d_in[1];   // (E,E)
    const float* bd = (const float*)d_in[2];   // (E,)
    float* out = (float*)d_out;                // (B,E,W)

    char* ws = (char*)d_ws;
    unsigned short* xS   = (unsigned short*)(ws);                    // 16 MB
    unsigned short* xdi  = (unsigned short*)(ws + (16u << 20));      // 16 MB
    unsigned short* MT   = (unsigned short*)(ws + (32u << 20));      //  2 MB
    unsigned short* tws  = (unsigned short*)(ws + (34u << 20));      // 16 MB
    float*          pl   = (float*)(ws + (50u << 20));               //  2 MB (1.25 used)
    unsigned short* pacc = (unsigned short*)(ws + (52u << 20));      // 20 MB

    hipLaunchKernelGGL(k_prep,   dim3(512),  dim3(256), 0, stream, x, xS, xdi);
    hipLaunchKernelGGL(k_MT,     dim3(512),  dim3(256), 0, stream, Md, MT);
    hipLaunchKernelGGL(k_attn,   dim3(2560), dim3(256), 0, stream, xS, xdi, pacc, pl);
    hipLaunchKernelGGL(k_reduce, dim3(1024), dim3(256), 0, stream, pacc, pl, tws);
    hipLaunchKernelGGL(k_gemm,   dim3(B*(E/128)*(Wn/128)), dim3(256), 0, stream, MT, tws, bd, out);
}

// Round 14
// 109.154 us; speedup vs baseline: 2.3114x; 1.0429x over previous
//
#include <hip/hip_runtime.h>
#include <hip/hip_bf16.h>

// Problem constants
constexpr int B  = 4;
constexpr int E  = 1024;
constexpr int Wn = 2048;
constexpr int H  = 16;
constexpr int Dh = 64;   // E / H

typedef short bf16x8 __attribute__((ext_vector_type(8)));
typedef float f32x4  __attribute__((ext_vector_type(4)));

__device__ inline unsigned short f2bf(float f){
    unsigned int u = __builtin_bit_cast(unsigned int, f);
    u = (u + 0x7fffu + ((u >> 16) & 1u)) >> 16;   // RNE
    return (unsigned short)u;
}
__device__ inline float bf2f(unsigned short u){
    return __builtin_bit_cast(float, (unsigned int)u << 16);
}
__device__ inline unsigned int pack_bf16_trunc(float lo, float hi){
    return __builtin_amdgcn_perm(__builtin_bit_cast(unsigned int, hi),
                                 __builtin_bit_cast(unsigned int, lo), 0x07060302u);
}
__device__ inline float exp2_fast(float x){ return __builtin_amdgcn_exp2f(x); }
// LDS column swizzle for the prep tile
__device__ inline int SW(int c){ return c ^ (((c >> 5) & 7) << 2); }

// global -> LDS direct DMA, 16B per lane
#define GLDS(g, l) __builtin_amdgcn_global_load_lds( \
    (const __attribute__((address_space(1))) void*)(g), \
    (__attribute__((address_space(3))) void*)(l), 16, 0, 0)

// 19 work items per head (256-query superblocks sb2=0..7, kv chunks of <=8
// stages, near-uniform, heavy-first). SLOTT=-1 -> direct tws write.
__device__ __constant__ signed char SB2T[19] =
    {2,1,3,3,5,5,5,7,7,7,7,4,4,6,6,6,6,4,0};
__device__ __constant__ signed char KV64T[19] =
    {0,0,0,8,0,8,16,0,8,16,24,0,7,0,7,14,21,14,0};
__device__ __constant__ signed char NSTT[19] =
    {12,8,8,8,8,8,8,8,8,8,8,7,7,7,7,7,7,6,4};
__device__ __constant__ signed char SLOTT[19] =
    {-1,-1,0,1,5,6,7,12,13,14,15,2,3,8,9,10,11,4,-1};
__device__ __constant__ signed char LASTT[19] =
    {1,1,0,1,0,0,1,0,0,0,1,0,0,0,0,0,1,1,1};
// k_reduce tables for sb2=3..7
__device__ __constant__ signed char NCHT[5]   = {2,3,3,4,4};
__device__ __constant__ signed char SBASET[5] = {0,2,5,8,12};

// ---------------------------------------------------------------------------
// K_prep: x read once -> xS (shared scaled Q/K operand) + xdi (V, permuted)
// ---------------------------------------------------------------------------
__global__ __launch_bounds__(256) void k_prep(const float* __restrict__ x,
                                              unsigned short* __restrict__ xS,
                                              unsigned short* __restrict__ xdi){
    __shared__ float tile[64*257];
    const float cs = 0.2123304349f;   // sqrt(log2(e)/32)
    const int t  = threadIdx.x;
    const int bh = blockIdx.x >> 3;
    const int w0 = (blockIdx.x & 7) << 8;

    {
        const int r = t >> 2, seg = t & 3;
        const float* src = x + ((size_t)bh*64 + r)*Wn + w0 + seg*64;
        float* dst = tile + r*257;
        #pragma unroll
        for (int i = 0; i < 16; ++i){
            float4 v = *reinterpret_cast<const float4*>(src + i*4);
            int c0 = seg*64 + i*4;
            dst[SW(c0+0)] = v.x; dst[SW(c0+1)] = v.y;
            dst[SW(c0+2)] = v.z; dst[SW(c0+3)] = v.w;
        }
    }
    __syncthreads();

    {
        const int kgw = t & 3, g = (t >> 2) & 7, r0 = t >> 5;
        #pragma unroll
        for (int rr = 0; rr < 8; ++rr){
            const int r = r0*8 + rr;
            const float* base = tile + r*257;
            const int c0 = g*32 + 4*kgw;
            union { unsigned short us[8]; uint4 v; } u;
            #pragma unroll
            for (int j2 = 0; j2 < 4; ++j2){
                u.us[j2]   = f2bf(base[SW(c0 + j2)]);
                u.us[4+j2] = f2bf(base[SW(c0 + 16 + j2)]);
            }
            *reinterpret_cast<uint4*>(xdi + ((size_t)bh*64 + r)*Wn + w0 + g*32 + 8*kgw) = u.v;
        }
    }
    {
        const int w = t;
        #pragma unroll
        for (int dg = 0; dg < 8; ++dg){
            union { unsigned short us[8]; uint4 v; } u;
            #pragma unroll
            for (int i = 0; i < 8; ++i)
                u.us[i] = f2bf(tile[(dg*8 + i)*257 + SW(w)] * cs);
            *reinterpret_cast<uint4*>(xS + ((size_t)bh*Wn + w0 + w)*64 + dg*8) = u.v;
        }
    }
}

// ---------------------------------------------------------------------------
// K2: M_d -> MT (bf16 transposed)
// ---------------------------------------------------------------------------
__global__ void k_MT(const float* __restrict__ M, unsigned short* __restrict__ MT){
    int tid = blockIdx.x*256 + threadIdx.x;
    int f  = tid & (E-1);
    int eg = tid >> 10;
    union { unsigned short us[8]; uint4 v; } u;
    #pragma unroll
    for (int i = 0; i < 8; i++) u.us[i] = f2bf(M[(size_t)(eg*8+i)*E + f]);
    *reinterpret_cast<uint4*>(MT + (size_t)f*E + eg*8) = u.v;
}

// ---------------------------------------------------------------------------
// K3: flash attention, 8-WAVE blocks (512 thr) sharing one 32KB K/V double
// buffer: 256 queries/block, staging cost per wave halves, waves-per-LDS-byte
// doubles. Per 64-key stage: 1 K-GLDS + 1 V-GLDS per wave, vmcnt(2) pipeline.
// Work items from tables; single-chunk items write tws directly, multi-chunk
// items write additive (acc,l) partials (pacc lives in d_out, 32MB exact).
// ---------------------------------------------------------------------------
__global__ __launch_bounds__(512)
void k_attn(const unsigned short* __restrict__ xS,
            const unsigned short* __restrict__ xdi,
            unsigned short* __restrict__ tws,
            unsigned short* __restrict__ pacc,
            float* __restrict__ pl){
    __shared__ char Klds[2*8192];
    __shared__ char Vlds[2*8192];

    const int lane = threadIdx.x & 63;
    const int wv   = threadIdx.x >> 6;          // 0..7
    const int jl = lane & 15, kg = lane >> 4;
    const int sw = jl & 7;

    const int p    = blockIdx.x;
    const int xcd  = p & 7;
    const int hh   = (p >> 3) & 7;
    const int widx = p >> 6;                    // 0..18, heavy first
    const int bh   = xcd*8 + hh;                // heads pinned per XCD

    const int sb2  = SB2T[widx];
    const int kvb  = (int)KV64T[widx] * 64;
    const int nst  = NSTT[widx];
    const int slot = SLOTT[widx];
    const bool isLast = LASTT[widx] != 0;

    const int q0w = sb2*256 + wv*32;            // this wave's query base

    const bf16x8* xSr = reinterpret_cast<const bf16x8*>(xS + (size_t)bh*Wn*Dh);
    bf16x8 bq[2][2];
    #pragma unroll
    for (int jt = 0; jt < 2; jt++){
        bq[jt][0] = xSr[(q0w + jt*16 + jl)*8 + kg];
        bq[jt][1] = xSr[(q0w + jt*16 + jl)*8 + 4 + kg];
    }
    union { bf16x8 v; unsigned short us[8]; } ones;
    #pragma unroll
    for (int i2 = 0; i2 < 8; i2++) ones.us[i2] = 0x3F80;

    f32x4 acc[2][4] = {};
    f32x4 accl[2] = {};

    const char* Kg = (const char*)xS  + (size_t)bh*Wn*128;      // key rows, 128B
    const char* Vg = (const char*)xdi + (size_t)bh*Dh*(Wn*2);   // d rows, 4KB
    const int rloc = 8*wv + (lane >> 3);           // 0..63 (8 waves)
    const int ksw  = ((lane & 7) ^ (rloc & 7))*16; // pre-swizzled src col

    auto STAGE = [&](int buf, int kvT){
        const char* kg0 = Kg + (size_t)(kvT + rloc)*128 + ksw;
        const char* vg0 = Vg + (size_t)rloc*(Wn*2) + kvT*2 + ksw;
        GLDS(kg0, Klds + buf*8192 + wv*1024);
        GLDS(vg0, Vlds + buf*8192 + wv*1024);
    };

    auto computeS = [&](int buf, int s, bool dg){
        const char* Kb = Klds + buf*8192;
        const char* Vb = Vlds + buf*8192;
        const int r0 = s*32 + jl, r1 = r0 + 16;
        bf16x8 k0a = *(const bf16x8*)(Kb + r0*128 + ((kg    )^sw)*16);
        bf16x8 k0b = *(const bf16x8*)(Kb + r0*128 + ((kg + 4)^sw)*16);
        bf16x8 k1a = *(const bf16x8*)(Kb + r1*128 + ((kg    )^sw)*16);
        bf16x8 k1b = *(const bf16x8*)(Kb + r1*128 + ((kg + 4)^sw)*16);
        const int vsw = ((s*4 + kg)^sw)*16;
        bf16x8 v0 = *(const bf16x8*)(Vb + (     jl)*128 + vsw);
        bf16x8 v1 = *(const bf16x8*)(Vb + (16 + jl)*128 + vsw);
        bf16x8 v2 = *(const bf16x8*)(Vb + (32 + jl)*128 + vsw);
        bf16x8 v3 = *(const bf16x8*)(Vb + (48 + jl)*128 + vsw);

        #pragma unroll
        for (int jt = 0; jt < 2; jt++){
            f32x4 s0 = {0,0,0,0}, s1 = {0,0,0,0};
            s0 = __builtin_amdgcn_mfma_f32_16x16x32_bf16(k0a, bq[jt][0], s0, 0,0,0);
            s0 = __builtin_amdgcn_mfma_f32_16x16x32_bf16(k0b, bq[jt][1], s0, 0,0,0);
            s1 = __builtin_amdgcn_mfma_f32_16x16x32_bf16(k1a, bq[jt][0], s1, 0,0,0);
            s1 = __builtin_amdgcn_mfma_f32_16x16x32_bf16(k1b, bq[jt][1], s1, 0,0,0);

            union { bf16x8 v; unsigned int w[4]; } bp;
            if (!dg){
                bp.w[0] = pack_bf16_trunc(exp2_fast(s0[0]), exp2_fast(s0[1]));
                bp.w[1] = pack_bf16_trunc(exp2_fast(s0[2]), exp2_fast(s0[3]));
                bp.w[2] = pack_bf16_trunc(exp2_fast(s1[0]), exp2_fast(s1[1]));
                bp.w[3] = pack_bf16_trunc(exp2_fast(s1[2]), exp2_fast(s1[3]));
            } else {
                const int lim = 16*jt + jl;
                float pp[8];
                #pragma unroll
                for (int r = 0; r < 4; r++){
                    int c = 4*kg + r;
                    pp[r]   = (c      <= lim) ? exp2_fast(s0[r]) : 0.f;
                    pp[4+r] = (c + 16 <= lim) ? exp2_fast(s1[r]) : 0.f;
                }
                bp.w[0] = pack_bf16_trunc(pp[0], pp[1]);
                bp.w[1] = pack_bf16_trunc(pp[2], pp[3]);
                bp.w[2] = pack_bf16_trunc(pp[4], pp[5]);
                bp.w[3] = pack_bf16_trunc(pp[6], pp[7]);
            }
            accl[jt] = __builtin_amdgcn_mfma_f32_16x16x32_bf16(ones.v, bp.v, accl[jt], 0,0,0);
            acc[jt][0] = __builtin_amdgcn_mfma_f32_16x16x32_bf16(v0, bp.v, acc[jt][0], 0,0,0);
            acc[jt][1] = __builtin_amdgcn_mfma_f32_16x16x32_bf16(v1, bp.v, acc[jt][1], 0,0,0);
            acc[jt][2] = __builtin_amdgcn_mfma_f32_16x16x32_bf16(v2, bp.v, acc[jt][2], 0,0,0);
            acc[jt][3] = __builtin_amdgcn_mfma_f32_16x16x32_bf16(v3, bp.v, acc[jt][3], 0,0,0);
        }
    };

    STAGE(0, kvb);
    for (int t = 0; t < nst; ++t){
        const int kvT = kvb + 64*t;
        if (t + 1 < nst){
            STAGE((t+1)&1, kvT + 64);
            asm volatile("s_waitcnt vmcnt(2)" ::: "memory");
        } else {
            asm volatile("s_waitcnt vmcnt(0)" ::: "memory");
        }
        __builtin_amdgcn_s_barrier();
        __builtin_amdgcn_sched_barrier(0);
        #pragma unroll
        for (int s = 0; s < 2; ++s){
            const int kv = kvT + 32*s;
            if (kv > q0w) continue;
            computeS(t & 1, s, isLast && (kv == q0w));
        }
        asm volatile("s_waitcnt lgkmcnt(0)" ::: "memory");
        __builtin_amdgcn_sched_barrier(0);
        __builtin_amdgcn_s_barrier();
    }

    if (slot < 0){
        // ---- direct epilogue: normalize, write tws
        #pragma unroll
        for (int jt = 0; jt < 2; jt++){
            const float inv = 1.0f / accl[jt][0];
            unsigned short* trow = tws + ((size_t)(bh >> 4)*Wn + q0w + jt*16 + jl)*E + (bh & 15)*Dh;
            #pragma unroll
            for (int dt = 0; dt < 4; dt++){
                union { unsigned short us[4]; ushort4 v; } o;
                #pragma unroll
                for (int r = 0; r < 4; r++) o.us[r] = f2bf(acc[jt][dt][r] * inv);
                *reinterpret_cast<ushort4*>(trow + dt*16 + 4*kg) = o.v;
            }
        }
    } else {
        // ---- partial epilogue: bf16 acc + f32 l
        const int gslot = bh*16 + slot;
        if (kg == 0){
            pl[(size_t)gslot*256 + wv*32 + jl]      = accl[0][0];
            pl[(size_t)gslot*256 + wv*32 + 16 + jl] = accl[1][0];
        }
        unsigned short* pa = pacc + (size_t)gslot*16384;
        #pragma unroll
        for (int jt = 0; jt < 2; jt++){
            #pragma unroll
            for (int dt = 0; dt < 4; dt++){
                union { unsigned short us[4]; ushort4 v; } o;
                #pragma unroll
                for (int r = 0; r < 4; r++) o.us[r] = f2bf(acc[jt][dt][r]);
                *reinterpret_cast<ushort4*>(pa + (wv*32 + jt*16 + jl)*64 + dt*16 + 4*kg) = o.v;
            }
        }
    }
}

// ---------------------------------------------------------------------------
// K3b: combine 2-4 chunk partials per (head, sb2 in 3..7), normalize, write
// tws. Grid 320 = 64 heads x 5 superblocks; 512 threads (q=t>>1, d-half=t&1).
// ---------------------------------------------------------------------------
__global__ __launch_bounds__(512) void k_reduce(const unsigned short* __restrict__ pacc,
                                                const float* __restrict__ pl,
                                                unsigned short* __restrict__ tws){
    const int g   = blockIdx.x;
    const int bh  = g / 5, s5 = g % 5;
    const int sb2 = 3 + s5;
    const int t   = threadIdx.x;
    const int qq  = t >> 1;
    const int db  = (t & 1)*32;
    const int nch   = NCHT[s5];
    const int slot0 = bh*16 + SBASET[s5];

    float l = 0.f;
    float a[32];
    #pragma unroll
    for (int i = 0; i < 32; ++i) a[i] = 0.f;
    for (int c = 0; c < nch; ++c){
        l += pl[(size_t)(slot0 + c)*256 + qq];
        const unsigned short* pa = pacc + (size_t)(slot0 + c)*16384 + qq*64 + db;
        #pragma unroll
        for (int i = 0; i < 4; ++i){
            union { uint4 v; unsigned short us[8]; } r0;
            r0.v = *reinterpret_cast<const uint4*>(pa + i*8);
            #pragma unroll
            for (int j2 = 0; j2 < 8; ++j2) a[i*8 + j2] += bf2f(r0.us[j2]);
        }
    }
    const float inv = 1.0f / l;
    unsigned short* tw = tws + ((size_t)(bh >> 4)*Wn + sb2*256 + qq)*E + (bh & 15)*Dh + db;
    #pragma unroll
    for (int i = 0; i < 4; ++i){
        union { uint4 v; unsigned short us[8]; } o;
        #pragma unroll
        for (int j2 = 0; j2 < 8; ++j2) o.us[j2] = f2bf(a[i*8 + j2] * inv);
        *reinterpret_cast<uint4*>(tw + i*8) = o.v;
    }
}

// ---------------------------------------------------------------------------
// K4: out[b][f][w] = sum_e MT[f][e] * t_ws[b][w][e] + b_d[f]   (r12, LDS-staged)
// ---------------------------------------------------------------------------
__global__ __launch_bounds__(256)
void k_gemm(const unsigned short* __restrict__ MT,
            const unsigned short* __restrict__ tws,
            const float* __restrict__ bd,
            float* __restrict__ out){
    __shared__ char Alds[2*16384];
    __shared__ char Blds[2*16384];

    const int lane = threadIdx.x & 63;
    const int wv   = threadIdx.x >> 6;
    const int jl = lane & 15, kg = lane >> 4;
    const int sw = jl & 7;

    const int p   = blockIdx.x;
    const int blk = (p & 7)*64 + (p >> 3);
    const int b  = blk >> 7;
    const int t2 = blk & 127;
    const int fblk = (t2 >> 4)*128;
    const int wblk = (t2 & 15)*128;
    const int f0 = fblk + (wv >> 1)*64;
    const int w0 = wblk + (wv &  1)*64;

    const char* Ag = (const char*)MT + (size_t)fblk*E*2;
    const char* Bg = (const char*)tws + ((size_t)b*Wn + wblk)*E*2;
    const int rloc = 8*wv + (lane >> 3);
    const int scw  = ((lane & 7) ^ (lane >> 3))*16;

    auto STAGE = [&](int buf, int e0){
        char* Ab = Alds + buf*16384;
        char* Bb = Blds + buf*16384;
        const char* ag = Ag + (size_t)rloc*(E*2) + e0*2 + scw;
        const char* bg = Bg + (size_t)rloc*(E*2) + e0*2 + scw;
        #pragma unroll
        for (int g = 0; g < 4; ++g){
            GLDS(ag + (size_t)g*32*(E*2), Ab + g*4096 + wv*1024);
            GLDS(bg + (size_t)g*32*(E*2), Bb + g*4096 + wv*1024);
        }
    };

    f32x4 acc[4][4] = {};

    auto COMP = [&](int buf){
        const char* Ab = Alds + buf*16384 + ((wv >> 1)*64)*128;
        const char* Bb = Blds + buf*16384 + ((wv &  1)*64)*128;
        #pragma unroll
        for (int h = 0; h < 2; ++h){
            const int cs = ((h*4 + kg) ^ sw)*16;
            bf16x8 am[4], bn[4];
            #pragma unroll
            for (int i = 0; i < 4; i++) am[i] = *(const bf16x8*)(Ab + (i*16 + jl)*128 + cs);
            #pragma unroll
            for (int j = 0; j < 4; j++) bn[j] = *(const bf16x8*)(Bb + (j*16 + jl)*128 + cs);
            #pragma unroll
            for (int i = 0; i < 4; i++)
                #pragma unroll
                for (int j = 0; j < 4; j++)
                    acc[i][j] = __builtin_amdgcn_mfma_f32_16x16x32_bf16(am[i], bn[j], acc[i][j], 0,0,0);
        }
    };

    STAGE(0, 0);
    for (int t = 0; t < 16; ++t){
        if (t < 15){
            STAGE((t+1)&1, (t+1)*64);
            asm volatile("s_waitcnt vmcnt(8)" ::: "memory");
        } else {
            asm volatile("s_waitcnt vmcnt(0)" ::: "memory");
        }
        __builtin_amdgcn_s_barrier();
        __builtin_amdgcn_sched_barrier(0);
        COMP(t & 1);
        asm volatile("s_waitcnt lgkmcnt(0)" ::: "memory");
        __builtin_amdgcn_sched_barrier(0);
        __builtin_amdgcn_s_barrier();
    }

    #pragma unroll
    for (int i = 0; i < 4; i++){
        float bias[4];
        #pragma unroll
        for (int r = 0; r < 4; r++) bias[r] = bd[f0 + i*16 + 4*kg + r];
        #pragma unroll
        for (int j = 0; j < 4; j++){
            #pragma unroll
            for (int r = 0; r < 4; r++){
                out[((size_t)b*E + f0 + i*16 + 4*kg + r)*Wn + w0 + j*16 + jl]
                    = acc[i][j][r] + bias[r];
            }
        }
    }
}

// ---------------------------------------------------------------------------
extern "C" void kernel_launch(void* const* d_in, const int* in_sizes, int n_in,
                              void* d_out, int out_size, void* d_ws, size_t ws_size,
                              hipStream_t stream) {
    const float* x  = (const float*)d_in[0];   // (B,E,W)
    const float* Md = (const float*)d_in[1];   // (E,E)
    const float* bd = (const float*)d_in[2];   // (E,)
    float* out = (float*)d_out;                // (B,E,W)

    char* ws = (char*)d_ws;
    unsigned short* xS   = (unsigned short*)(ws);                    // 16 MB
    unsigned short* xdi  = (unsigned short*)(ws + (16u << 20));      // 16 MB
    unsigned short* MT   = (unsigned short*)(ws + (32u << 20));      //  2 MB
    unsigned short* tws  = (unsigned short*)(ws + (34u << 20));      // 16 MB
    float*          pl   = (float*)(ws + (50u << 20));               //  1 MB
    // pacc lives in d_out (exactly 32MB = 64 heads x 16 slots x 32KB);
    // d_out is dead until k_gemm fully overwrites it afterwards.
    unsigned short* pacc = (unsigned short*)d_out;

    hipLaunchKernelGGL(k_prep,   dim3(512),  dim3(256), 0, stream, x, xS, xdi);
    hipLaunchKernelGGL(k_MT,     dim3(512),  dim3(256), 0, stream, Md, MT);
    hipLaunchKernelGGL(k_attn,   dim3(19*64), dim3(512), 0, stream, xS, xdi, tws, pacc, pl);
    hipLaunchKernelGGL(k_reduce, dim3(320),  dim3(512), 0, stream, pacc, pl, tws);
    hipLaunchKernelGGL(k_gemm,   dim3(B*(E/128)*(Wn/128)), dim3(256), 0, stream, MT, tws, bd, out);
}